// Round 10
// baseline (211.907 us; speedup 1.0000x reference)
//
#include <hip/hip_runtime.h>
#include <hip/hip_bf16.h>
#include <stdint.h>

// ---------------- types ----------------
typedef __bf16 bf16x8 __attribute__((ext_vector_type(8)));
typedef short  s16x8  __attribute__((ext_vector_type(8)));
typedef float  f32x4  __attribute__((ext_vector_type(4)));
typedef float  f32x16 __attribute__((ext_vector_type(16)));
typedef unsigned int u32x2 __attribute__((ext_vector_type(2)));
typedef unsigned int u32x4 __attribute__((ext_vector_type(4)));

__device__ __forceinline__ f32x4 mfma16(s16x8 a, s16x8 b, f32x4 c) {
  return __builtin_amdgcn_mfma_f32_16x16x32_bf16(
      __builtin_bit_cast(bf16x8, a), __builtin_bit_cast(bf16x8, b), c, 0, 0, 0);
}
__device__ __forceinline__ f32x16 mfma32(s16x8 a, s16x8 b, f32x16 c) {
  return __builtin_amdgcn_mfma_f32_32x32x16_bf16(
      __builtin_bit_cast(bf16x8, a), __builtin_bit_cast(bf16x8, b), c, 0, 0, 0);
}

__device__ __forceinline__ void load_lds16(const void* g, void* l) {
  __builtin_amdgcn_global_load_lds(
      (const __attribute__((address_space(1))) void*)g,
      (__attribute__((address_space(3))) void*)l,
      16, 0, 0);
}

__device__ __forceinline__ float exp2fast(float x) {
  float r; asm("v_exp_f32 %0, %1" : "=v"(r) : "v"(x)); return r;
}
__device__ __forceinline__ unsigned cvtpk_bf16(float lo, float hi) {
  unsigned r; asm("v_cvt_pk_bf16_f32 %0, %1, %2" : "=v"(r) : "v"(lo), "v"(hi)); return r;
}
__device__ __forceinline__ float bf16lo_f(unsigned u) {
  return __builtin_bit_cast(float, u << 16);
}
__device__ __forceinline__ float bf16hi_f(unsigned u) {
  return __builtin_bit_cast(float, u & 0xffff0000u);
}
__device__ __forceinline__ void plswap2(unsigned a, unsigned b, int hi,
                                        unsigned& x, unsigned& y) {
#if __has_builtin(__builtin_amdgcn_permlane32_swap)
  auto r = __builtin_amdgcn_permlane32_swap(a, b, false, false);
  x = (unsigned)r[0]; y = (unsigned)r[1];
#else
  unsigned ax = (unsigned)__shfl_xor((int)a, 32);
  unsigned bx = (unsigned)__shfl_xor((int)b, 32);
  x = hi ? bx : a;
  y = hi ? b : ax;
#endif
}

// ---------------- conversion kernels ----------------
__global__ void cvt_x(const float* __restrict__ in, __hip_bfloat16* __restrict__ out, int n) {
  int i = (blockIdx.x * 256 + threadIdx.x) << 2;
  if (i >= n) return;
  float4 v = *(const float4*)(in + i);
  out[i + 0] = __float2bfloat16(v.x);
  out[i + 1] = __float2bfloat16(v.y);
  out[i + 2] = __float2bfloat16(v.z);
  out[i + 3] = __float2bfloat16(v.w);
}

// All 4 weights [1024][1024] f32 -> bf16 transposed into one contiguous region.
__global__ void cvt_w_t4(const float* __restrict__ W0, const float* __restrict__ W1,
                         const float* __restrict__ W2, const float* __restrict__ W3,
                         __hip_bfloat16* __restrict__ outbase) {
  __shared__ float t[64][65];
  const int sel = blockIdx.x >> 8;
  const int bid = blockIdx.x & 255;
  const float* in = sel == 0 ? W0 : sel == 1 ? W1 : sel == 2 ? W2 : W3;
  __hip_bfloat16* out = outbase + (size_t)sel * 1048576;
  const int tx = threadIdx.x & 63, ty = threadIdx.x >> 6;  // ty 0..3
  const int bk = bid & 15, bn = bid >> 4;
  const int k0 = bk * 64, n0 = bn * 64;
#pragma unroll
  for (int j = 0; j < 16; ++j)
    t[ty + j * 4][tx] = in[(size_t)(k0 + ty + j * 4) * 1024 + n0 + tx];
  __syncthreads();
#pragma unroll
  for (int j = 0; j < 16; ++j)
    out[(size_t)(n0 + ty + j * 4) * 1024 + k0 + tx] =
        __float2bfloat16(t[tx][ty + j * 4]);
}

// ---------------- fused QKV GEMM (unchanged) ----------------
__launch_bounds__(256, 2)
__global__ void gemm_qkv(const __hip_bfloat16* __restrict__ A,
                         const __hip_bfloat16* __restrict__ Bt,
                         const float* __restrict__ bq,
                         const float* __restrict__ bk,
                         const float* __restrict__ bv,
                         __hip_bfloat16* __restrict__ Qb,
                         __hip_bfloat16* __restrict__ Kb,
                         __hip_bfloat16* __restrict__ Vt) {
  __shared__ __align__(16) __hip_bfloat16 As[128 * 64];
  __shared__ __align__(16) __hip_bfloat16 Bs[128 * 64];
  const int tid  = threadIdx.x;
  const int lane = tid & 63;
  const int wv   = tid >> 6;
  const int l15  = lane & 15;
  const int lhi  = lane >> 4;

  const int bid = blockIdx.x;
  const int lb = (bid & 7) * 192 + (bid >> 3);
  const int bm = lb / 24;
  const int bn = lb % 24;
  const int m0 = bm << 7, n0 = bn << 7;
  const int wr = wv >> 1, wc = wv & 1;

  f32x4 acc[4][4];
  const f32x4 z = {0.f, 0.f, 0.f, 0.f};
#pragma unroll
  for (int i = 0; i < 4; ++i)
#pragma unroll
    for (int j = 0; j < 4; ++j) acc[i][j] = z;

  const int lrow = lane >> 3;
  const int seg2 = (lane & 7) ^ lrow;

  for (int kt = 0; kt < 16; ++kt) {
    __syncthreads();
    const int gk = (kt << 6) + (seg2 << 3);
#pragma unroll
    for (int j = 0; j < 4; ++j) {
      const int c = (wv << 2) + j;
      const int row = (c << 3) + lrow;
      load_lds16(A  + (((size_t)(m0 + row)) << 10) + gk, &As[c << 9]);
      load_lds16(Bt + (((size_t)(n0 + row)) << 10) + gk, &Bs[c << 9]);
    }
    __syncthreads();

#pragma unroll
    for (int kk = 0; kk < 2; ++kk) {
      s16x8 af[4], bfr[4];
#pragma unroll
      for (int mi = 0; mi < 4; ++mi) {
        const int row = (wr << 6) + (mi << 4) + l15;
        const int off = (row << 7) + ((((kk << 2) | lhi) ^ (row & 7)) << 4);
        af[mi] = *(const s16x8*)((const char*)As + off);
      }
#pragma unroll
      for (int ni = 0; ni < 4; ++ni) {
        const int row = (wc << 6) + (ni << 4) + l15;
        const int off = (row << 7) + ((((kk << 2) | lhi) ^ (row & 7)) << 4);
        bfr[ni] = *(const s16x8*)((const char*)Bs + off);
      }
#pragma unroll
      for (int mi = 0; mi < 4; ++mi)
#pragma unroll
        for (int ni = 0; ni < 4; ++ni)
          acc[mi][ni] = mfma16(af[mi], bfr[ni], acc[mi][ni]);
    }
  }

  const int sel = n0 >> 10;  // 0=Q, 1=K, 2=V (block-uniform)
  const float* bp = sel == 0 ? bq : sel == 1 ? bk : bv;
#pragma unroll
  for (int ni = 0; ni < 4; ++ni) {
    const int col = n0 + (wc << 6) + (ni << 4) + l15;
    const int c10 = col & 1023;
    const float bval = bp[c10];
    if (sel == 2) {
      const int h = c10 >> 6, d = c10 & 63;
#pragma unroll
      for (int mi = 0; mi < 4; ++mi) {
        const int row0 = m0 + (wr << 6) + (mi << 4) + (lhi << 2);
#pragma unroll
        for (int r = 0; r < 4; ++r) {
          const int row = row0 + r;
          const int bb = row >> 11, s = row & 2047;
          Vt[(((size_t)(bb * 16 + h) * 64 + d) << 11) + s] =
              __float2bfloat16(acc[mi][ni][r] + bval);
        }
      }
    } else {
      __hip_bfloat16* dst = sel == 0 ? Qb : Kb;
#pragma unroll
      for (int mi = 0; mi < 4; ++mi) {
        const int row0 = m0 + (wr << 6) + (mi << 4) + (lhi << 2);
#pragma unroll
        for (int r = 0; r < 4; ++r)
          dst[(((size_t)(row0 + r)) << 10) + c10] =
              __float2bfloat16(acc[mi][ni][r] + bval);
      }
    }
  }
}

// ---------------- out-projection GEMM (unchanged) ----------------
__launch_bounds__(256, 2)
__global__ void gemm_out(const __hip_bfloat16* __restrict__ A,
                         const __hip_bfloat16* __restrict__ Bt,
                         const float* __restrict__ bias,
                         float* __restrict__ Cout) {
  __shared__ __align__(16) __hip_bfloat16 As[128 * 64];
  __shared__ __align__(16) __hip_bfloat16 Bs[128 * 64];
  const int tid  = threadIdx.x;
  const int lane = tid & 63;
  const int wv   = tid >> 6;
  const int l15  = lane & 15;
  const int lhi  = lane >> 4;

  const int bid = blockIdx.x;
  const int lb = (bid & 7) * 64 + (bid >> 3);
  const int bm = lb >> 3;
  const int bn = lb & 7;
  const int m0 = bm << 7, n0 = bn << 7;
  const int wr = wv >> 1, wc = wv & 1;

  f32x4 acc[4][4];
  const f32x4 z = {0.f, 0.f, 0.f, 0.f};
#pragma unroll
  for (int i = 0; i < 4; ++i)
#pragma unroll
    for (int j = 0; j < 4; ++j) acc[i][j] = z;

  const int lrow = lane >> 3;
  const int seg2 = (lane & 7) ^ lrow;

  for (int kt = 0; kt < 16; ++kt) {
    __syncthreads();
    const int gk = (kt << 6) + (seg2 << 3);
#pragma unroll
    for (int j = 0; j < 4; ++j) {
      const int c = (wv << 2) + j;
      const int row = (c << 3) + lrow;
      load_lds16(A  + (((size_t)(m0 + row)) << 10) + gk, &As[c << 9]);
      load_lds16(Bt + (((size_t)(n0 + row)) << 10) + gk, &Bs[c << 9]);
    }
    __syncthreads();

#pragma unroll
    for (int kk = 0; kk < 2; ++kk) {
      s16x8 af[4], bfr[4];
#pragma unroll
      for (int mi = 0; mi < 4; ++mi) {
        const int row = (wr << 6) + (mi << 4) + l15;
        const int off = (row << 7) + ((((kk << 2) | lhi) ^ (row & 7)) << 4);
        af[mi] = *(const s16x8*)((const char*)As + off);
      }
#pragma unroll
      for (int ni = 0; ni < 4; ++ni) {
        const int row = (wc << 6) + (ni << 4) + l15;
        const int off = (row << 7) + ((((kk << 2) | lhi) ^ (row & 7)) << 4);
        bfr[ni] = *(const s16x8*)((const char*)Bs + off);
      }
#pragma unroll
      for (int mi = 0; mi < 4; ++mi)
#pragma unroll
        for (int ni = 0; ni < 4; ++ni)
          acc[mi][ni] = mfma16(af[mi], bfr[ni], acc[mi][ni]);
    }
  }

#pragma unroll
  for (int ni = 0; ni < 4; ++ni) {
    const int col = n0 + (wc << 6) + (ni << 4) + l15;
    const float bval = bias[col];
#pragma unroll
    for (int mi = 0; mi < 4; ++mi) {
      const int row0 = m0 + (wr << 6) + (mi << 4) + (lhi << 2);
#pragma unroll
      for (int r = 0; r < 4; ++r)
        Cout[(((size_t)(row0 + r)) << 10) + col] = acc[mi][ni][r] + bval;
    }
  }
}

// ---------------- flash attention: triple-buffer, counted vmcnt (T3/T4) ----------------
// Qb,Kb: [B*S][1024] bf16; Vt: [B,H,HD,S] bf16; mask: [B,S] f32; ctx: [B*S][1024] bf16
// Block = 4 waves, one (b,h), 128 q-rows. Wave owns 32 q (q = lane&31).
// K/V 64x64 bf16 tiles TRIPLE-buffered in LDS (XOR-swizzled via pre-swizzled
// global source). Pipeline: iter t waits vmcnt(8) (only the t-2 staging group),
// leaving the t+1 group in flight across the raw s_barrier; issues t+2 after.
// p = exp2(s*log2e/8 + pen - 16); row-constant factor cancels in normalization.
__launch_bounds__(256, 4)
__global__ void attn32(const __hip_bfloat16* __restrict__ Qb,
                       const __hip_bfloat16* __restrict__ Kb,
                       const __hip_bfloat16* __restrict__ Vt,
                       const float* __restrict__ mask,
                       __hip_bfloat16* __restrict__ ctx) {
  __shared__ __align__(16) __hip_bfloat16 K_lds[3][4096];  // [64 k][64 d] swizzled
  __shared__ __align__(16) __hip_bfloat16 V_lds[3][4096];  // [64 d][64 k] swizzled
  __shared__ __align__(16) unsigned pen_lds[1024];         // 2048 bf16 (packed pairs)

  const int tid = threadIdx.x;
  const int lane = tid & 63, wv = tid >> 6;
  const int l31 = lane & 31, hi = lane >> 5;

  const int bid = blockIdx.x;
  const int lb = (bid & 7) * 128 + (bid >> 3);
  const int qt = lb & 15;
  const int bh = lb >> 4;
  const int h = bh & 15, b = bh >> 4;

  const int srow = lane >> 3;
  const int sseg = (lane & 7) ^ srow;
  const char* kg[2];
  const char* vg[2];
#pragma unroll
  for (int p = 0; p < 2; ++p) {
    const int row = (p * 4 + wv) * 8 + srow;
    kg[p] = (const char*)Kb +
            (((size_t)(b * 2048 + row) << 10) + h * 64 + sseg * 8) * 2;
    vg[p] = (const char*)Vt +
            (((size_t)(bh * 64 + row) << 11) + sseg * 8) * 2;
  }

  int offs[8];
#pragma unroll
  for (int i = 0; i < 8; ++i) {
    const int row7 = l31 & 7;
    offs[i] = ((i >> 2) << 12) + (l31 << 7) +
              ((((((i & 3) << 1) | hi)) ^ row7) << 4);
  }

  // ---- prologue: stage tiles 0 and 1 ----
#pragma unroll
  for (int p = 0; p < 2; ++p) {
    load_lds16(kg[p], &K_lds[0][(p * 4 + wv) * 512]);
    load_lds16(vg[p], &V_lds[0][(p * 4 + wv) * 512]);
  }
#pragma unroll
  for (int p = 0; p < 2; ++p) {
    load_lds16(kg[p] + (1 << 17), &K_lds[1][(p * 4 + wv) * 512]);
    load_lds16(vg[p] + (1 << 7),  &V_lds[1][(p * 4 + wv) * 512]);
  }
  {
    // pen2[k] = -1e6*log2e*(1-mask[b][k]) - 16, stored as bf16 pairs
    const float* mrow = mask + b * 2048;
    const int i0 = tid * 8;
    float4 m0 = *(const float4*)(mrow + i0);
    float4 m1 = *(const float4*)(mrow + i0 + 4);
    u32x4 u;
    u[0] = cvtpk_bf16(fmaf(m0.x, 1442695.04f, -1442711.04f),
                      fmaf(m0.y, 1442695.04f, -1442711.04f));
    u[1] = cvtpk_bf16(fmaf(m0.z, 1442695.04f, -1442711.04f),
                      fmaf(m0.w, 1442695.04f, -1442711.04f));
    u[2] = cvtpk_bf16(fmaf(m1.x, 1442695.04f, -1442711.04f),
                      fmaf(m1.y, 1442695.04f, -1442711.04f));
    u[3] = cvtpk_bf16(fmaf(m1.z, 1442695.04f, -1442711.04f),
                      fmaf(m1.w, 1442695.04f, -1442711.04f));
    *(u32x4*)&pen_lds[tid * 4] = u;
  }

  const int q0 = qt * 128 + wv * 32;

  s16x8 qf[4];
  {
    const __hip_bfloat16* qp =
        Qb + (size_t)(b * 2048 + q0 + l31) * 1024 + h * 64 + hi * 8;
#pragma unroll
    for (int d = 0; d < 4; ++d) qf[d] = *(const s16x8*)(qp + d * 16);
  }

  f32x16 oa0, oa1;
#pragma unroll
  for (int i = 0; i < 16; ++i) { oa0[i] = 0.f; oa1[i] = 0.f; }
  float lsum[4] = {0.f, 0.f, 0.f, 0.f};

  __syncthreads();  // one-time full drain: tiles 0,1 + pen ready everywhere

  for (int t = 0; t < 32; ++t) {
    // ---- counted wait: only the staging group for buf[t%3] (issued at t-2) ----
    if (t == 31) {
      asm volatile("s_waitcnt vmcnt(0)" ::: "memory");
    } else {
      asm volatile("s_waitcnt vmcnt(8)" ::: "memory");
    }
    __builtin_amdgcn_sched_barrier(0);
    __builtin_amdgcn_s_barrier();

    const int cur = t % 3;
    // ---- issue staging of tile t+2 (WAR on this buf covered by the barrier) ----
    if (t < 30) {
      const int nxt = (t + 2) % 3;
      const size_t kadv = (size_t)(t + 2) << 17;
      const size_t vadv = (size_t)(t + 2) << 7;
#pragma unroll
      for (int p = 0; p < 2; ++p) {
        load_lds16(kg[p] + kadv, &K_lds[nxt][(p * 4 + wv) * 512]);
        load_lds16(vg[p] + vadv, &V_lds[nxt][(p * 4 + wv) * 512]);
      }
    }

    const char* kb = (const char*)K_lds[cur];
    f32x16 sa[2];
#pragma unroll
    for (int i = 0; i < 16; ++i) { sa[0][i] = 0.f; sa[1][i] = 0.f; }
    {
      s16x8 kf[4];
#pragma unroll
      for (int i = 0; i < 4; ++i) kf[i] = *(const s16x8*)(kb + offs[i]);
      __builtin_amdgcn_s_setprio(1);
#pragma unroll
      for (int d = 0; d < 4; ++d) sa[0] = mfma32(kf[d], qf[d], sa[0]);
      __builtin_amdgcn_s_setprio(0);
#pragma unroll
      for (int i = 0; i < 4; ++i) kf[i] = *(const s16x8*)(kb + offs[4 + i]);
      __builtin_amdgcn_s_setprio(1);
#pragma unroll
      for (int d = 0; d < 4; ++d) sa[1] = mfma32(kf[d], qf[d], sa[1]);
      __builtin_amdgcn_s_setprio(0);
    }

    // ---- static-C softmax: p = exp2(s*log2e/8 + pen) ; pen bf16, broadcast reads ----
    const unsigned* pt = &pen_lds[t << 5];  // 64 bf16 = 32 u32 per tile
    float pq[32];
#pragma unroll
    for (int s = 0; s < 2; ++s)
#pragma unroll
      for (int a = 0; a < 4; ++a) {
        const u32x2 u = *(const u32x2*)(pt + s * 16 + a * 4 + hi * 2);
        const float pn0 = bf16lo_f(u[0]), pn1 = bf16hi_f(u[0]);
        const float pn2 = bf16lo_f(u[1]), pn3 = bf16hi_f(u[1]);
        const int ib = s * 16 + a * 4;
        float p;
        p = exp2fast(fmaf(sa[s][a * 4 + 0], 0.18033688011112042f, pn0));
        pq[ib + 0] = p; lsum[0] += p;
        p = exp2fast(fmaf(sa[s][a * 4 + 1], 0.18033688011112042f, pn1));
        pq[ib + 1] = p; lsum[1] += p;
        p = exp2fast(fmaf(sa[s][a * 4 + 2], 0.18033688011112042f, pn2));
        pq[ib + 2] = p; lsum[2] += p;
        p = exp2fast(fmaf(sa[s][a * 4 + 3], 0.18033688011112042f, pn3));
        pq[ib + 3] = p; lsum[3] += p;
      }

    s16x8 pb[4];
#pragma unroll
    for (int ks = 0; ks < 4; ++ks) {
      const int base = (ks >> 1) * 16 + (ks & 1) * 8;
      const unsigned wa0 = cvtpk_bf16(pq[base + 0], pq[base + 1]);
      const unsigned wa1 = cvtpk_bf16(pq[base + 2], pq[base + 3]);
      const unsigned wb0 = cvtpk_bf16(pq[base + 4], pq[base + 5]);
      const unsigned wb1 = cvtpk_bf16(pq[base + 6], pq[base + 7]);
      unsigned x0, y0, x1, y1;
      plswap2(wa0, wb0, hi, x0, y0);
      plswap2(wa1, wb1, hi, x1, y1);
      u32x4 u = {x0, x1, y0, y1};
      pb[ks] = __builtin_bit_cast(s16x8, u);
    }

    const char* vb = (const char*)V_lds[cur];
    {
      s16x8 vf[4];
#pragma unroll
      for (int i = 0; i < 4; ++i) vf[i] = *(const s16x8*)(vb + offs[i]);
      __builtin_amdgcn_s_setprio(1);
#pragma unroll
      for (int ks = 0; ks < 4; ++ks) oa0 = mfma32(vf[ks], pb[ks], oa0);
      __builtin_amdgcn_s_setprio(0);
#pragma unroll
      for (int i = 0; i < 4; ++i) vf[i] = *(const s16x8*)(vb + offs[4 + i]);
      __builtin_amdgcn_s_setprio(1);
#pragma unroll
      for (int ks = 0; ks < 4; ++ks) oa1 = mfma32(vf[ks], pb[ks], oa1);
      __builtin_amdgcn_s_setprio(0);
    }
  }

  float lrun = (lsum[0] + lsum[1]) + (lsum[2] + lsum[3]);
  lrun += __shfl_xor(lrun, 32);
  const float inv = 1.0f / lrun;
  __hip_bfloat16* cp = ctx + (size_t)(b * 2048 + q0 + l31) * 1024 + h * 64 + hi * 4;
#pragma unroll
  for (int dt = 0; dt < 2; ++dt) {
#pragma unroll
    for (int g = 0; g < 4; ++g) {
      const float v0 = (dt ? oa1[4 * g + 0] : oa0[4 * g + 0]) * inv;
      const float v1 = (dt ? oa1[4 * g + 1] : oa0[4 * g + 1]) * inv;
      const float v2 = (dt ? oa1[4 * g + 2] : oa0[4 * g + 2]) * inv;
      const float v3 = (dt ? oa1[4 * g + 3] : oa0[4 * g + 3]) * inv;
      u32x2 u;
      u[0] = cvtpk_bf16(v0, v1);
      u[1] = cvtpk_bf16(v2, v3);
      *(u32x2*)(cp + dt * 32 + g * 8) = u;
    }
  }
}

// ---------------- launch ----------------
extern "C" void kernel_launch(void* const* d_in, const int* in_sizes, int n_in,
                              void* d_out, int out_size, void* d_ws, size_t ws_size,
                              hipStream_t stream) {
  const float* X    = (const float*)d_in[0];
  const float* mask = (const float*)d_in[1];
  const float* Wq   = (const float*)d_in[2];
  const float* bq   = (const float*)d_in[3];
  const float* Wk   = (const float*)d_in[4];
  const float* bk   = (const float*)d_in[5];
  const float* Wv   = (const float*)d_in[6];
  const float* bvv  = (const float*)d_in[7];
  const float* Wo   = (const float*)d_in[8];
  const float* bo   = (const float*)d_in[9];
  float* out = (float*)d_out;
  char* ws = (char*)d_ws;

  __hip_bfloat16* Xb   = (__hip_bfloat16*)(ws + 0);        // 16 MiB, reused as ctx
  __hip_bfloat16* ctx  = Xb;
  __hip_bfloat16* Wcat = (__hip_bfloat16*)(ws + 16777216); // Wq^T|Wk^T|Wv^T|Wo^T (8 MiB)
  __hip_bfloat16* Wot  = (__hip_bfloat16*)(ws + 23068672);
  __hip_bfloat16* Qb   = (__hip_bfloat16*)(ws + 25165824);
  __hip_bfloat16* Kb   = (__hip_bfloat16*)(ws + 41943040);
  __hip_bfloat16* Vt   = (__hip_bfloat16*)(ws + 58720256);

  cvt_x<<<8192, 256, 0, stream>>>(X, Xb, 8388608);
  cvt_w_t4<<<1024, 256, 0, stream>>>(Wq, Wk, Wv, Wo, Wcat);

  gemm_qkv<<<1536, 256, 0, stream>>>(Xb, Wcat, bq, bk, bvv, Qb, Kb, Vt);

  attn32<<<1024, 256, 0, stream>>>(Qb, Kb, Vt, mask, ctx);

  gemm_out<<<512, 256, 0, stream>>>(ctx, Wot, bo, out);
}

// Round 11
// 197.693 us; speedup vs baseline: 1.0719x; 1.0719x over previous
//
#include <hip/hip_runtime.h>
#include <hip/hip_bf16.h>
#include <stdint.h>

// ---------------- types ----------------
typedef __bf16 bf16x8 __attribute__((ext_vector_type(8)));
typedef short  s16x8  __attribute__((ext_vector_type(8)));
typedef float  f32x4  __attribute__((ext_vector_type(4)));
typedef float  f32x16 __attribute__((ext_vector_type(16)));
typedef unsigned int u32x2 __attribute__((ext_vector_type(2)));
typedef unsigned int u32x4 __attribute__((ext_vector_type(4)));

__device__ __forceinline__ f32x4 mfma16(s16x8 a, s16x8 b, f32x4 c) {
  return __builtin_amdgcn_mfma_f32_16x16x32_bf16(
      __builtin_bit_cast(bf16x8, a), __builtin_bit_cast(bf16x8, b), c, 0, 0, 0);
}
__device__ __forceinline__ f32x16 mfma32(s16x8 a, s16x8 b, f32x16 c) {
  return __builtin_amdgcn_mfma_f32_32x32x16_bf16(
      __builtin_bit_cast(bf16x8, a), __builtin_bit_cast(bf16x8, b), c, 0, 0, 0);
}

__device__ __forceinline__ void load_lds16(const void* g, void* l) {
  __builtin_amdgcn_global_load_lds(
      (const __attribute__((address_space(1))) void*)g,
      (__attribute__((address_space(3))) void*)l,
      16, 0, 0);
}

__device__ __forceinline__ float exp2fast(float x) {
  float r; asm("v_exp_f32 %0, %1" : "=v"(r) : "v"(x)); return r;
}
__device__ __forceinline__ unsigned cvtpk_bf16(float lo, float hi) {
  unsigned r; asm("v_cvt_pk_bf16_f32 %0, %1, %2" : "=v"(r) : "v"(lo), "v"(hi)); return r;
}
__device__ __forceinline__ float bf16lo_f(unsigned u) {
  return __builtin_bit_cast(float, u << 16);
}
__device__ __forceinline__ float bf16hi_f(unsigned u) {
  return __builtin_bit_cast(float, u & 0xffff0000u);
}
__device__ __forceinline__ void plswap2(unsigned a, unsigned b, int hi,
                                        unsigned& x, unsigned& y) {
#if __has_builtin(__builtin_amdgcn_permlane32_swap)
  auto r = __builtin_amdgcn_permlane32_swap(a, b, false, false);
  x = (unsigned)r[0]; y = (unsigned)r[1];
#else
  unsigned ax = (unsigned)__shfl_xor((int)a, 32);
  unsigned bx = (unsigned)__shfl_xor((int)b, 32);
  x = hi ? bx : a;
  y = hi ? b : ax;
#endif
}

// ---------------- fused conversion kernel ----------------
// blocks [0,8192): X f32 -> Xb bf16 (1024 elems/block)
// blocks [8192,9216): weight sel=(blk>>8)&3, 64x64 LDS tile transpose f32->bf16
__global__ void cvt_all(const float* __restrict__ X,
                        const float* __restrict__ W0, const float* __restrict__ W1,
                        const float* __restrict__ W2, const float* __restrict__ W3,
                        __hip_bfloat16* __restrict__ Xb,
                        __hip_bfloat16* __restrict__ Wcat) {
  __shared__ float t[64][65];
  const int blk = blockIdx.x;
  if (blk < 8192) {
    int i = (blk * 256 + threadIdx.x) << 2;
    float4 v = *(const float4*)(X + i);
    Xb[i + 0] = __float2bfloat16(v.x);
    Xb[i + 1] = __float2bfloat16(v.y);
    Xb[i + 2] = __float2bfloat16(v.z);
    Xb[i + 3] = __float2bfloat16(v.w);
    return;
  }
  const int wblk = blk - 8192;
  const int sel = wblk >> 8;
  const int bid = wblk & 255;
  const float* in = sel == 0 ? W0 : sel == 1 ? W1 : sel == 2 ? W2 : W3;
  __hip_bfloat16* out = Wcat + (size_t)sel * 1048576;
  const int tx = threadIdx.x & 63, ty = threadIdx.x >> 6;  // ty 0..3
  const int bk = bid & 15, bn = bid >> 4;
  const int k0 = bk * 64, n0 = bn * 64;
#pragma unroll
  for (int j = 0; j < 16; ++j)
    t[ty + j * 4][tx] = in[(size_t)(k0 + ty + j * 4) * 1024 + n0 + tx];
  __syncthreads();
#pragma unroll
  for (int j = 0; j < 16; ++j)
    out[(size_t)(n0 + ty + j * 4) * 1024 + k0 + tx] =
        __float2bfloat16(t[tx][ty + j * 4]);
}

// ---------------- fused QKV GEMM (unchanged) ----------------
__launch_bounds__(256, 2)
__global__ void gemm_qkv(const __hip_bfloat16* __restrict__ A,
                         const __hip_bfloat16* __restrict__ Bt,
                         const float* __restrict__ bq,
                         const float* __restrict__ bk,
                         const float* __restrict__ bv,
                         __hip_bfloat16* __restrict__ Qb,
                         __hip_bfloat16* __restrict__ Kb,
                         __hip_bfloat16* __restrict__ Vt) {
  __shared__ __align__(16) __hip_bfloat16 As[128 * 64];
  __shared__ __align__(16) __hip_bfloat16 Bs[128 * 64];
  const int tid  = threadIdx.x;
  const int lane = tid & 63;
  const int wv   = tid >> 6;
  const int l15  = lane & 15;
  const int lhi  = lane >> 4;

  const int bid = blockIdx.x;
  const int lb = (bid & 7) * 192 + (bid >> 3);
  const int bm = lb / 24;
  const int bn = lb % 24;
  const int m0 = bm << 7, n0 = bn << 7;
  const int wr = wv >> 1, wc = wv & 1;

  f32x4 acc[4][4];
  const f32x4 z = {0.f, 0.f, 0.f, 0.f};
#pragma unroll
  for (int i = 0; i < 4; ++i)
#pragma unroll
    for (int j = 0; j < 4; ++j) acc[i][j] = z;

  const int lrow = lane >> 3;
  const int seg2 = (lane & 7) ^ lrow;

  for (int kt = 0; kt < 16; ++kt) {
    __syncthreads();
    const int gk = (kt << 6) + (seg2 << 3);
#pragma unroll
    for (int j = 0; j < 4; ++j) {
      const int c = (wv << 2) + j;
      const int row = (c << 3) + lrow;
      load_lds16(A  + (((size_t)(m0 + row)) << 10) + gk, &As[c << 9]);
      load_lds16(Bt + (((size_t)(n0 + row)) << 10) + gk, &Bs[c << 9]);
    }
    __syncthreads();

#pragma unroll
    for (int kk = 0; kk < 2; ++kk) {
      s16x8 af[4], bfr[4];
#pragma unroll
      for (int mi = 0; mi < 4; ++mi) {
        const int row = (wr << 6) + (mi << 4) + l15;
        const int off = (row << 7) + ((((kk << 2) | lhi) ^ (row & 7)) << 4);
        af[mi] = *(const s16x8*)((const char*)As + off);
      }
#pragma unroll
      for (int ni = 0; ni < 4; ++ni) {
        const int row = (wc << 6) + (ni << 4) + l15;
        const int off = (row << 7) + ((((kk << 2) | lhi) ^ (row & 7)) << 4);
        bfr[ni] = *(const s16x8*)((const char*)Bs + off);
      }
#pragma unroll
      for (int mi = 0; mi < 4; ++mi)
#pragma unroll
        for (int ni = 0; ni < 4; ++ni)
          acc[mi][ni] = mfma16(af[mi], bfr[ni], acc[mi][ni]);
    }
  }

  const int sel = n0 >> 10;  // 0=Q, 1=K, 2=V (block-uniform)
  const float* bp = sel == 0 ? bq : sel == 1 ? bk : bv;
#pragma unroll
  for (int ni = 0; ni < 4; ++ni) {
    const int col = n0 + (wc << 6) + (ni << 4) + l15;
    const int c10 = col & 1023;
    const float bval = bp[c10];
    if (sel == 2) {
      const int h = c10 >> 6, d = c10 & 63;
#pragma unroll
      for (int mi = 0; mi < 4; ++mi) {
        const int row0 = m0 + (wr << 6) + (mi << 4) + (lhi << 2);
#pragma unroll
        for (int r = 0; r < 4; ++r) {
          const int row = row0 + r;
          const int bb = row >> 11, s = row & 2047;
          Vt[(((size_t)(bb * 16 + h) * 64 + d) << 11) + s] =
              __float2bfloat16(acc[mi][ni][r] + bval);
        }
      }
    } else {
      __hip_bfloat16* dst = sel == 0 ? Qb : Kb;
#pragma unroll
      for (int mi = 0; mi < 4; ++mi) {
        const int row0 = m0 + (wr << 6) + (mi << 4) + (lhi << 2);
#pragma unroll
        for (int r = 0; r < 4; ++r)
          dst[(((size_t)(row0 + r)) << 10) + c10] =
              __float2bfloat16(acc[mi][ni][r] + bval);
      }
    }
  }
}

// ---------------- out-projection GEMM (unchanged) ----------------
__launch_bounds__(256, 2)
__global__ void gemm_out(const __hip_bfloat16* __restrict__ A,
                         const __hip_bfloat16* __restrict__ Bt,
                         const float* __restrict__ bias,
                         float* __restrict__ Cout) {
  __shared__ __align__(16) __hip_bfloat16 As[128 * 64];
  __shared__ __align__(16) __hip_bfloat16 Bs[128 * 64];
  const int tid  = threadIdx.x;
  const int lane = tid & 63;
  const int wv   = tid >> 6;
  const int l15  = lane & 15;
  const int lhi  = lane >> 4;

  const int bid = blockIdx.x;
  const int lb = (bid & 7) * 64 + (bid >> 3);
  const int bm = lb >> 3;
  const int bn = lb & 7;
  const int m0 = bm << 7, n0 = bn << 7;
  const int wr = wv >> 1, wc = wv & 1;

  f32x4 acc[4][4];
  const f32x4 z = {0.f, 0.f, 0.f, 0.f};
#pragma unroll
  for (int i = 0; i < 4; ++i)
#pragma unroll
    for (int j = 0; j < 4; ++j) acc[i][j] = z;

  const int lrow = lane >> 3;
  const int seg2 = (lane & 7) ^ lrow;

  for (int kt = 0; kt < 16; ++kt) {
    __syncthreads();
    const int gk = (kt << 6) + (seg2 << 3);
#pragma unroll
    for (int j = 0; j < 4; ++j) {
      const int c = (wv << 2) + j;
      const int row = (c << 3) + lrow;
      load_lds16(A  + (((size_t)(m0 + row)) << 10) + gk, &As[c << 9]);
      load_lds16(Bt + (((size_t)(n0 + row)) << 10) + gk, &Bs[c << 9]);
    }
    __syncthreads();

#pragma unroll
    for (int kk = 0; kk < 2; ++kk) {
      s16x8 af[4], bfr[4];
#pragma unroll
      for (int mi = 0; mi < 4; ++mi) {
        const int row = (wr << 6) + (mi << 4) + l15;
        const int off = (row << 7) + ((((kk << 2) | lhi) ^ (row & 7)) << 4);
        af[mi] = *(const s16x8*)((const char*)As + off);
      }
#pragma unroll
      for (int ni = 0; ni < 4; ++ni) {
        const int row = (wc << 6) + (ni << 4) + l15;
        const int off = (row << 7) + ((((kk << 2) | lhi) ^ (row & 7)) << 4);
        bfr[ni] = *(const s16x8*)((const char*)Bs + off);
      }
#pragma unroll
      for (int mi = 0; mi < 4; ++mi)
#pragma unroll
        for (int ni = 0; ni < 4; ++ni)
          acc[mi][ni] = mfma16(af[mi], bfr[ni], acc[mi][ni]);
    }
  }

#pragma unroll
  for (int ni = 0; ni < 4; ++ni) {
    const int col = n0 + (wc << 6) + (ni << 4) + l15;
    const float bval = bias[col];
#pragma unroll
    for (int mi = 0; mi < 4; ++mi) {
      const int row0 = m0 + (wr << 6) + (mi << 4) + (lhi << 2);
#pragma unroll
      for (int r = 0; r < 4; ++r)
        Cout[(((size_t)(row0 + r)) << 10) + col] = acc[mi][ni][r] + bval;
    }
  }
}

// ---------------- flash attention: r9 body + all-ones-mask fast path ----------------
// Qb,Kb: [B*S][1024] bf16; Vt: [B,H,HD,S] bf16; mask: [B,S] f32; ctx: [B*S][1024] bf16
// Block = 4 waves, one (b,h), 128 q-rows. Wave owns 32 q (q = lane&31).
// K/V 64x64 bf16 tiles double-buffered in LDS (XOR-swizzled via pre-swizzled
// global source). p = exp2(s*log2e/8 + pen - 16); row-constant factor cancels
// in normalization. If the whole mask row is 1.0 (detected via per-wave ballot),
// pen is the constant -16 and the per-iter pen LDS read + unpack is skipped.
__launch_bounds__(256, 4)
__global__ void attn32(const __hip_bfloat16* __restrict__ Qb,
                       const __hip_bfloat16* __restrict__ Kb,
                       const __hip_bfloat16* __restrict__ Vt,
                       const float* __restrict__ mask,
                       __hip_bfloat16* __restrict__ ctx) {
  __shared__ __align__(16) __hip_bfloat16 K_lds[2][4096];  // [64 k][64 d] swizzled
  __shared__ __align__(16) __hip_bfloat16 V_lds[2][4096];  // [64 d][64 k] swizzled
  __shared__ __align__(16) unsigned pen_lds[1024];         // 2048 bf16 (packed pairs)
  __shared__ int wflag[4];

  const int tid = threadIdx.x;
  const int lane = tid & 63, wv = tid >> 6;
  const int l31 = lane & 31, hi = lane >> 5;

  const int bid = blockIdx.x;
  const int lb = (bid & 7) * 128 + (bid >> 3);
  const int qt = lb & 15;
  const int bh = lb >> 4;
  const int h = bh & 15, b = bh >> 4;

  const int srow = lane >> 3;
  const int sseg = (lane & 7) ^ srow;
  const char* kg[2];
  const char* vg[2];
#pragma unroll
  for (int p = 0; p < 2; ++p) {
    const int row = (p * 4 + wv) * 8 + srow;
    kg[p] = (const char*)Kb +
            (((size_t)(b * 2048 + row) << 10) + h * 64 + sseg * 8) * 2;
    vg[p] = (const char*)Vt +
            (((size_t)(bh * 64 + row) << 11) + sseg * 8) * 2;
  }

  int offs[8];
#pragma unroll
  for (int i = 0; i < 8; ++i) {
    const int row7 = l31 & 7;
    offs[i] = ((i >> 2) << 12) + (l31 << 7) +
              ((((((i & 3) << 1) | hi)) ^ row7) << 4);
  }

#pragma unroll
  for (int p = 0; p < 2; ++p) {
    load_lds16(kg[p], &K_lds[0][(p * 4 + wv) * 512]);
    load_lds16(vg[p], &V_lds[0][(p * 4 + wv) * 512]);
  }
  {
    // pen2[k] = -1e6*log2e*(1-mask[b][k]) - 16, stored as bf16 pairs
    const float* mrow = mask + b * 2048;
    const int i0 = tid * 8;
    float4 m0 = *(const float4*)(mrow + i0);
    float4 m1 = *(const float4*)(mrow + i0 + 4);
    const bool ok = (m0.x == 1.f) & (m0.y == 1.f) & (m0.z == 1.f) & (m0.w == 1.f) &
                    (m1.x == 1.f) & (m1.y == 1.f) & (m1.z == 1.f) & (m1.w == 1.f);
    wflag[wv] = (__ballot(ok) == ~0ull) ? 1 : 0;  // same-value write per wave
    u32x4 u;
    u[0] = cvtpk_bf16(fmaf(m0.x, 1442695.04f, -1442711.04f),
                      fmaf(m0.y, 1442695.04f, -1442711.04f));
    u[1] = cvtpk_bf16(fmaf(m0.z, 1442695.04f, -1442711.04f),
                      fmaf(m0.w, 1442695.04f, -1442711.04f));
    u[2] = cvtpk_bf16(fmaf(m1.x, 1442695.04f, -1442711.04f),
                      fmaf(m1.y, 1442695.04f, -1442711.04f));
    u[3] = cvtpk_bf16(fmaf(m1.z, 1442695.04f, -1442711.04f),
                      fmaf(m1.w, 1442695.04f, -1442711.04f));
    *(u32x4*)&pen_lds[tid * 4] = u;
  }

  const int q0 = qt * 128 + wv * 32;

  s16x8 qf[4];
  {
    const __hip_bfloat16* qp =
        Qb + (size_t)(b * 2048 + q0 + l31) * 1024 + h * 64 + hi * 8;
#pragma unroll
    for (int d = 0; d < 4; ++d) qf[d] = *(const s16x8*)(qp + d * 16);
  }

  f32x16 oa0, oa1;
#pragma unroll
  for (int i = 0; i < 16; ++i) { oa0[i] = 0.f; oa1[i] = 0.f; }
  float lsum[4] = {0.f, 0.f, 0.f, 0.f};

  __syncthreads();
  const bool fast = (wflag[0] & wflag[1] & wflag[2] & wflag[3]) != 0;

  const float SC = 0.18033688011112042f;  // log2(e)/8

  for (int t = 0; t < 32; ++t) {
    const int cur = t & 1;
    if (t < 31) {
      const size_t kadv = (size_t)(t + 1) << 17;
      const size_t vadv = (size_t)(t + 1) << 7;
#pragma unroll
      for (int p = 0; p < 2; ++p) {
        load_lds16(kg[p] + kadv, &K_lds[cur ^ 1][(p * 4 + wv) * 512]);
        load_lds16(vg[p] + vadv, &V_lds[cur ^ 1][(p * 4 + wv) * 512]);
      }
    }

    const char* kb = (const char*)K_lds[cur];
    f32x16 sa[2];
#pragma unroll
    for (int i = 0; i < 16; ++i) { sa[0][i] = 0.f; sa[1][i] = 0.f; }
    {
      s16x8 kf[4];
#pragma unroll
      for (int i = 0; i < 4; ++i) kf[i] = *(const s16x8*)(kb + offs[i]);
      __builtin_amdgcn_s_setprio(1);
#pragma unroll
      for (int d = 0; d < 4; ++d) sa[0] = mfma32(kf[d], qf[d], sa[0]);
      __builtin_amdgcn_s_setprio(0);
#pragma unroll
      for (int i = 0; i < 4; ++i) kf[i] = *(const s16x8*)(kb + offs[4 + i]);
      __builtin_amdgcn_s_setprio(1);
#pragma unroll
      for (int d = 0; d < 4; ++d) sa[1] = mfma32(kf[d], qf[d], sa[1]);
      __builtin_amdgcn_s_setprio(0);
    }

    // ---- static-C softmax: p = exp2(s*log2e/8 + pen) ----
    float pq[32];
    if (fast) {
      // mask row all ones: pen is the constant -16
#pragma unroll
      for (int s = 0; s < 2; ++s)
#pragma unroll
        for (int a = 0; a < 4; ++a) {
          const int ib = s * 16 + a * 4;
#pragma unroll
          for (int r = 0; r < 4; ++r) {
            const float p = exp2fast(fmaf(sa[s][a * 4 + r], SC, -16.0f));
            pq[ib + r] = p;
            lsum[r] += p;
          }
        }
    } else {
      const unsigned* pt = &pen_lds[t << 5];  // 64 bf16 = 32 u32 per tile
#pragma unroll
      for (int s = 0; s < 2; ++s)
#pragma unroll
        for (int a = 0; a < 4; ++a) {
          const u32x2 u = *(const u32x2*)(pt + s * 16 + a * 4 + hi * 2);
          const float pn0 = bf16lo_f(u[0]), pn1 = bf16hi_f(u[0]);
          const float pn2 = bf16lo_f(u[1]), pn3 = bf16hi_f(u[1]);
          const int ib = s * 16 + a * 4;
          float p;
          p = exp2fast(fmaf(sa[s][a * 4 + 0], SC, pn0));
          pq[ib + 0] = p; lsum[0] += p;
          p = exp2fast(fmaf(sa[s][a * 4 + 1], SC, pn1));
          pq[ib + 1] = p; lsum[1] += p;
          p = exp2fast(fmaf(sa[s][a * 4 + 2], SC, pn2));
          pq[ib + 2] = p; lsum[2] += p;
          p = exp2fast(fmaf(sa[s][a * 4 + 3], SC, pn3));
          pq[ib + 3] = p; lsum[3] += p;
        }
    }

    s16x8 pb[4];
#pragma unroll
    for (int ks = 0; ks < 4; ++ks) {
      const int base = (ks >> 1) * 16 + (ks & 1) * 8;
      const unsigned wa0 = cvtpk_bf16(pq[base + 0], pq[base + 1]);
      const unsigned wa1 = cvtpk_bf16(pq[base + 2], pq[base + 3]);
      const unsigned wb0 = cvtpk_bf16(pq[base + 4], pq[base + 5]);
      const unsigned wb1 = cvtpk_bf16(pq[base + 6], pq[base + 7]);
      unsigned x0, y0, x1, y1;
      plswap2(wa0, wb0, hi, x0, y0);
      plswap2(wa1, wb1, hi, x1, y1);
      u32x4 u = {x0, x1, y0, y1};
      pb[ks] = __builtin_bit_cast(s16x8, u);
    }

    const char* vb = (const char*)V_lds[cur];
    {
      s16x8 vf[4];
#pragma unroll
      for (int i = 0; i < 4; ++i) vf[i] = *(const s16x8*)(vb + offs[i]);
      __builtin_amdgcn_s_setprio(1);
#pragma unroll
      for (int ks = 0; ks < 4; ++ks) oa0 = mfma32(vf[ks], pb[ks], oa0);
      __builtin_amdgcn_s_setprio(0);
#pragma unroll
      for (int i = 0; i < 4; ++i) vf[i] = *(const s16x8*)(vb + offs[4 + i]);
      __builtin_amdgcn_s_setprio(1);
#pragma unroll
      for (int ks = 0; ks < 4; ++ks) oa1 = mfma32(vf[ks], pb[ks], oa1);
      __builtin_amdgcn_s_setprio(0);
    }

    __syncthreads();
  }

  float lrun = (lsum[0] + lsum[1]) + (lsum[2] + lsum[3]);
  lrun += __shfl_xor(lrun, 32);
  const float inv = 1.0f / lrun;
  __hip_bfloat16* cp = ctx + (size_t)(b * 2048 + q0 + l31) * 1024 + h * 64 + hi * 4;
#pragma unroll
  for (int dt = 0; dt < 2; ++dt) {
#pragma unroll
    for (int g = 0; g < 4; ++g) {
      const float v0 = (dt ? oa1[4 * g + 0] : oa0[4 * g + 0]) * inv;
      const float v1 = (dt ? oa1[4 * g + 1] : oa0[4 * g + 1]) * inv;
      const float v2 = (dt ? oa1[4 * g + 2] : oa0[4 * g + 2]) * inv;
      const float v3 = (dt ? oa1[4 * g + 3] : oa0[4 * g + 3]) * inv;
      u32x2 u;
      u[0] = cvtpk_bf16(v0, v1);
      u[1] = cvtpk_bf16(v2, v3);
      *(u32x2*)(cp + dt * 32 + g * 8) = u;
    }
  }
}

// ---------------- launch ----------------
extern "C" void kernel_launch(void* const* d_in, const int* in_sizes, int n_in,
                              void* d_out, int out_size, void* d_ws, size_t ws_size,
                              hipStream_t stream) {
  const float* X    = (const float*)d_in[0];
  const float* mask = (const float*)d_in[1];
  const float* Wq   = (const float*)d_in[2];
  const float* bq   = (const float*)d_in[3];
  const float* Wk   = (const float*)d_in[4];
  const float* bk   = (const float*)d_in[5];
  const float* Wv   = (const float*)d_in[6];
  const float* bvv  = (const float*)d_in[7];
  const float* Wo   = (const float*)d_in[8];
  const float* bo   = (const float*)d_in[9];
  float* out = (float*)d_out;
  char* ws = (char*)d_ws;

  __hip_bfloat16* Xb   = (__hip_bfloat16*)(ws + 0);        // 16 MiB, reused as ctx
  __hip_bfloat16* ctx  = Xb;
  __hip_bfloat16* Wcat = (__hip_bfloat16*)(ws + 16777216); // Wq^T|Wk^T|Wv^T|Wo^T (8 MiB)
  __hip_bfloat16* Wot  = (__hip_bfloat16*)(ws + 23068672);
  __hip_bfloat16* Qb   = (__hip_bfloat16*)(ws + 25165824);
  __hip_bfloat16* Kb   = (__hip_bfloat16*)(ws + 41943040);
  __hip_bfloat16* Vt   = (__hip_bfloat16*)(ws + 58720256);

  cvt_all<<<9216, 256, 0, stream>>>(X, Wq, Wk, Wv, Wo, Xb, Wcat);

  gemm_qkv<<<1536, 256, 0, stream>>>(Xb, Wcat, bq, bk, bvv, Qb, Kb, Vt);

  attn32<<<1024, 256, 0, stream>>>(Qb, Kb, Vt, mask, ctx);

  gemm_out<<<512, 256, 0, stream>>>(ctx, Wot, bo, out);
}

// Round 12
// 187.284 us; speedup vs baseline: 1.1315x; 1.0556x over previous
//
#include <hip/hip_runtime.h>
#include <hip/hip_bf16.h>
#include <stdint.h>

// ---------------- types ----------------
typedef __bf16 bf16x8 __attribute__((ext_vector_type(8)));
typedef short  s16x8  __attribute__((ext_vector_type(8)));
typedef float  f32x4  __attribute__((ext_vector_type(4)));
typedef float  f32x16 __attribute__((ext_vector_type(16)));
typedef unsigned int u32x2 __attribute__((ext_vector_type(2)));
typedef unsigned int u32x4 __attribute__((ext_vector_type(4)));

__device__ __forceinline__ f32x4 mfma16(s16x8 a, s16x8 b, f32x4 c) {
  return __builtin_amdgcn_mfma_f32_16x16x32_bf16(
      __builtin_bit_cast(bf16x8, a), __builtin_bit_cast(bf16x8, b), c, 0, 0, 0);
}
__device__ __forceinline__ f32x16 mfma32(s16x8 a, s16x8 b, f32x16 c) {
  return __builtin_amdgcn_mfma_f32_32x32x16_bf16(
      __builtin_bit_cast(bf16x8, a), __builtin_bit_cast(bf16x8, b), c, 0, 0, 0);
}

__device__ __forceinline__ void load_lds16(const void* g, void* l) {
  __builtin_amdgcn_global_load_lds(
      (const __attribute__((address_space(1))) void*)g,
      (__attribute__((address_space(3))) void*)l,
      16, 0, 0);
}

__device__ __forceinline__ float exp2fast(float x) {
  float r; asm("v_exp_f32 %0, %1" : "=v"(r) : "v"(x)); return r;
}
__device__ __forceinline__ unsigned cvtpk_bf16(float lo, float hi) {
  unsigned r; asm("v_cvt_pk_bf16_f32 %0, %1, %2" : "=v"(r) : "v"(lo), "v"(hi)); return r;
}
__device__ __forceinline__ void plswap2(unsigned a, unsigned b, int hi,
                                        unsigned& x, unsigned& y) {
#if __has_builtin(__builtin_amdgcn_permlane32_swap)
  auto r = __builtin_amdgcn_permlane32_swap(a, b, false, false);
  x = (unsigned)r[0]; y = (unsigned)r[1];
#else
  unsigned ax = (unsigned)__shfl_xor((int)a, 32);
  unsigned bx = (unsigned)__shfl_xor((int)b, 32);
  x = hi ? bx : a;
  y = hi ? b : ax;
#endif
}

// ---------------- fused conversion kernel ----------------
// blocks [0,8192): X f32 -> Xb bf16 (1024 elems/block)
// blocks [8192,9216): weight sel=(blk>>8)&3, 64x64 LDS tile transpose f32->bf16
__global__ void cvt_all(const float* __restrict__ X,
                        const float* __restrict__ W0, const float* __restrict__ W1,
                        const float* __restrict__ W2, const float* __restrict__ W3,
                        __hip_bfloat16* __restrict__ Xb,
                        __hip_bfloat16* __restrict__ Wcat) {
  __shared__ float t[64][65];
  const int blk = blockIdx.x;
  if (blk < 8192) {
    int i = (blk * 256 + threadIdx.x) << 2;
    float4 v = *(const float4*)(X + i);
    Xb[i + 0] = __float2bfloat16(v.x);
    Xb[i + 1] = __float2bfloat16(v.y);
    Xb[i + 2] = __float2bfloat16(v.z);
    Xb[i + 3] = __float2bfloat16(v.w);
    return;
  }
  const int wblk = blk - 8192;
  const int sel = wblk >> 8;
  const int bid = wblk & 255;
  const float* in = sel == 0 ? W0 : sel == 1 ? W1 : sel == 2 ? W2 : W3;
  __hip_bfloat16* out = Wcat + (size_t)sel * 1048576;
  const int tx = threadIdx.x & 63, ty = threadIdx.x >> 6;  // ty 0..3
  const int bk = bid & 15, bn = bid >> 4;
  const int k0 = bk * 64, n0 = bn * 64;
#pragma unroll
  for (int j = 0; j < 16; ++j)
    t[ty + j * 4][tx] = in[(size_t)(k0 + ty + j * 4) * 1024 + n0 + tx];
  __syncthreads();
#pragma unroll
  for (int j = 0; j < 16; ++j)
    out[(size_t)(n0 + ty + j * 4) * 1024 + k0 + tx] =
        __float2bfloat16(t[tx][ty + j * 4]);
}

// ---------------- fused QKV GEMM (unchanged) ----------------
__launch_bounds__(256, 2)
__global__ void gemm_qkv(const __hip_bfloat16* __restrict__ A,
                         const __hip_bfloat16* __restrict__ Bt,
                         const float* __restrict__ bq,
                         const float* __restrict__ bk,
                         const float* __restrict__ bv,
                         __hip_bfloat16* __restrict__ Qb,
                         __hip_bfloat16* __restrict__ Kb,
                         __hip_bfloat16* __restrict__ Vt) {
  __shared__ __align__(16) __hip_bfloat16 As[128 * 64];
  __shared__ __align__(16) __hip_bfloat16 Bs[128 * 64];
  const int tid  = threadIdx.x;
  const int lane = tid & 63;
  const int wv   = tid >> 6;
  const int l15  = lane & 15;
  const int lhi  = lane >> 4;

  const int bid = blockIdx.x;
  const int lb = (bid & 7) * 192 + (bid >> 3);
  const int bm = lb / 24;
  const int bn = lb % 24;
  const int m0 = bm << 7, n0 = bn << 7;
  const int wr = wv >> 1, wc = wv & 1;

  f32x4 acc[4][4];
  const f32x4 z = {0.f, 0.f, 0.f, 0.f};
#pragma unroll
  for (int i = 0; i < 4; ++i)
#pragma unroll
    for (int j = 0; j < 4; ++j) acc[i][j] = z;

  const int lrow = lane >> 3;
  const int seg2 = (lane & 7) ^ lrow;

  for (int kt = 0; kt < 16; ++kt) {
    __syncthreads();
    const int gk = (kt << 6) + (seg2 << 3);
#pragma unroll
    for (int j = 0; j < 4; ++j) {
      const int c = (wv << 2) + j;
      const int row = (c << 3) + lrow;
      load_lds16(A  + (((size_t)(m0 + row)) << 10) + gk, &As[c << 9]);
      load_lds16(Bt + (((size_t)(n0 + row)) << 10) + gk, &Bs[c << 9]);
    }
    __syncthreads();

#pragma unroll
    for (int kk = 0; kk < 2; ++kk) {
      s16x8 af[4], bfr[4];
#pragma unroll
      for (int mi = 0; mi < 4; ++mi) {
        const int row = (wr << 6) + (mi << 4) + l15;
        const int off = (row << 7) + ((((kk << 2) | lhi) ^ (row & 7)) << 4);
        af[mi] = *(const s16x8*)((const char*)As + off);
      }
#pragma unroll
      for (int ni = 0; ni < 4; ++ni) {
        const int row = (wc << 6) + (ni << 4) + l15;
        const int off = (row << 7) + ((((kk << 2) | lhi) ^ (row & 7)) << 4);
        bfr[ni] = *(const s16x8*)((const char*)Bs + off);
      }
#pragma unroll
      for (int mi = 0; mi < 4; ++mi)
#pragma unroll
        for (int ni = 0; ni < 4; ++ni)
          acc[mi][ni] = mfma16(af[mi], bfr[ni], acc[mi][ni]);
    }
  }

  const int sel = n0 >> 10;  // 0=Q, 1=K, 2=V (block-uniform)
  const float* bp = sel == 0 ? bq : sel == 1 ? bk : bv;
#pragma unroll
  for (int ni = 0; ni < 4; ++ni) {
    const int col = n0 + (wc << 6) + (ni << 4) + l15;
    const int c10 = col & 1023;
    const float bval = bp[c10];
    if (sel == 2) {
      const int h = c10 >> 6, d = c10 & 63;
#pragma unroll
      for (int mi = 0; mi < 4; ++mi) {
        const int row0 = m0 + (wr << 6) + (mi << 4) + (lhi << 2);
#pragma unroll
        for (int r = 0; r < 4; ++r) {
          const int row = row0 + r;
          const int bb = row >> 11, s = row & 2047;
          Vt[(((size_t)(bb * 16 + h) * 64 + d) << 11) + s] =
              __float2bfloat16(acc[mi][ni][r] + bval);
        }
      }
    } else {
      __hip_bfloat16* dst = sel == 0 ? Qb : Kb;
#pragma unroll
      for (int mi = 0; mi < 4; ++mi) {
        const int row0 = m0 + (wr << 6) + (mi << 4) + (lhi << 2);
#pragma unroll
        for (int r = 0; r < 4; ++r)
          dst[(((size_t)(row0 + r)) << 10) + c10] =
              __float2bfloat16(acc[mi][ni][r] + bval);
      }
    }
  }
}

// ---------------- out-projection GEMM (unchanged) ----------------
__launch_bounds__(256, 2)
__global__ void gemm_out(const __hip_bfloat16* __restrict__ A,
                         const __hip_bfloat16* __restrict__ Bt,
                         const float* __restrict__ bias,
                         float* __restrict__ Cout) {
  __shared__ __align__(16) __hip_bfloat16 As[128 * 64];
  __shared__ __align__(16) __hip_bfloat16 Bs[128 * 64];
  const int tid  = threadIdx.x;
  const int lane = tid & 63;
  const int wv   = tid >> 6;
  const int l15  = lane & 15;
  const int lhi  = lane >> 4;

  const int bid = blockIdx.x;
  const int lb = (bid & 7) * 64 + (bid >> 3);
  const int bm = lb >> 3;
  const int bn = lb & 7;
  const int m0 = bm << 7, n0 = bn << 7;
  const int wr = wv >> 1, wc = wv & 1;

  f32x4 acc[4][4];
  const f32x4 z = {0.f, 0.f, 0.f, 0.f};
#pragma unroll
  for (int i = 0; i < 4; ++i)
#pragma unroll
    for (int j = 0; j < 4; ++j) acc[i][j] = z;

  const int lrow = lane >> 3;
  const int seg2 = (lane & 7) ^ lrow;

  for (int kt = 0; kt < 16; ++kt) {
    __syncthreads();
    const int gk = (kt << 6) + (seg2 << 3);
#pragma unroll
    for (int j = 0; j < 4; ++j) {
      const int c = (wv << 2) + j;
      const int row = (c << 3) + lrow;
      load_lds16(A  + (((size_t)(m0 + row)) << 10) + gk, &As[c << 9]);
      load_lds16(Bt + (((size_t)(n0 + row)) << 10) + gk, &Bs[c << 9]);
    }
    __syncthreads();

#pragma unroll
    for (int kk = 0; kk < 2; ++kk) {
      s16x8 af[4], bfr[4];
#pragma unroll
      for (int mi = 0; mi < 4; ++mi) {
        const int row = (wr << 6) + (mi << 4) + l15;
        const int off = (row << 7) + ((((kk << 2) | lhi) ^ (row & 7)) << 4);
        af[mi] = *(const s16x8*)((const char*)As + off);
      }
#pragma unroll
      for (int ni = 0; ni < 4; ++ni) {
        const int row = (wc << 6) + (ni << 4) + l15;
        const int off = (row << 7) + ((((kk << 2) | lhi) ^ (row & 7)) << 4);
        bfr[ni] = *(const s16x8*)((const char*)Bs + off);
      }
#pragma unroll
      for (int mi = 0; mi < 4; ++mi)
#pragma unroll
        for (int ni = 0; ni < 4; ++ni)
          acc[mi][ni] = mfma16(af[mi], bfr[ni], acc[mi][ni]);
    }
  }

#pragma unroll
  for (int ni = 0; ni < 4; ++ni) {
    const int col = n0 + (wc << 6) + (ni << 4) + l15;
    const float bval = bias[col];
#pragma unroll
    for (int mi = 0; mi < 4; ++mi) {
      const int row0 = m0 + (wr << 6) + (mi << 4) + (lhi << 2);
#pragma unroll
      for (int r = 0; r < 4; ++r)
        Cout[(((size_t)(row0 + r)) << 10) + col] = acc[mi][ni][r] + bval;
    }
  }
}

// ---------------- flash attention: r8-exact (best measured: 92.5 us) ----------------
// Qb,Kb: [B*S][1024] bf16; Vt: [B,H,HD,S] bf16; mask: [B,S] f32; ctx: [B*S][1024] bf16
// Block = 4 waves, one (b,h), 128 q-rows. Wave owns 32 q (q = lane&31).
// K/V 64x64 bf16 tiles double-buffered in LDS (XOR-swizzled via pre-swizzled
// global source). p = exp2(s*log2e/8 + pen - 16); row-constant factor cancels
// in normalization, no overflow possible.
__launch_bounds__(256, 4)
__global__ void attn32(const __hip_bfloat16* __restrict__ Qb,
                       const __hip_bfloat16* __restrict__ Kb,
                       const __hip_bfloat16* __restrict__ Vt,
                       const float* __restrict__ mask,
                       __hip_bfloat16* __restrict__ ctx) {
  __shared__ __align__(16) __hip_bfloat16 K_lds[2][4096];  // [64 k][64 d] swizzled
  __shared__ __align__(16) __hip_bfloat16 V_lds[2][4096];  // [64 d][64 k] swizzled
  __shared__ float pen_lds[2048];

  const int tid = threadIdx.x;
  const int lane = tid & 63, wv = tid >> 6;
  const int l31 = lane & 31, hi = lane >> 5;

  const int bid = blockIdx.x;
  const int lb = (bid & 7) * 128 + (bid >> 3);
  const int qt = lb & 15;
  const int bh = lb >> 4;
  const int h = bh & 15, b = bh >> 4;

  const int srow = lane >> 3;
  const int sseg = (lane & 7) ^ srow;
  const char* kg[2];
  const char* vg[2];
#pragma unroll
  for (int p = 0; p < 2; ++p) {
    const int row = (p * 4 + wv) * 8 + srow;
    kg[p] = (const char*)Kb +
            (((size_t)(b * 2048 + row) << 10) + h * 64 + sseg * 8) * 2;
    vg[p] = (const char*)Vt +
            (((size_t)(bh * 64 + row) << 11) + sseg * 8) * 2;
  }

  int offs[8];
#pragma unroll
  for (int i = 0; i < 8; ++i) {
    const int row7 = l31 & 7;
    offs[i] = ((i >> 2) << 12) + (l31 << 7) +
              ((((((i & 3) << 1) | hi)) ^ row7) << 4);
  }

#pragma unroll
  for (int p = 0; p < 2; ++p) {
    load_lds16(kg[p], &K_lds[0][(p * 4 + wv) * 512]);
    load_lds16(vg[p], &V_lds[0][(p * 4 + wv) * 512]);
  }
  {
    const float* mrow = mask + b * 2048;
    const int i0 = tid * 8;
    float4 m0 = *(const float4*)(mrow + i0);
    float4 m1 = *(const float4*)(mrow + i0 + 4);
    pen_lds[i0 + 0] = fmaf(m0.x, 1442695.04f, -1442711.04f);
    pen_lds[i0 + 1] = fmaf(m0.y, 1442695.04f, -1442711.04f);
    pen_lds[i0 + 2] = fmaf(m0.z, 1442695.04f, -1442711.04f);
    pen_lds[i0 + 3] = fmaf(m0.w, 1442695.04f, -1442711.04f);
    pen_lds[i0 + 4] = fmaf(m1.x, 1442695.04f, -1442711.04f);
    pen_lds[i0 + 5] = fmaf(m1.y, 1442695.04f, -1442711.04f);
    pen_lds[i0 + 6] = fmaf(m1.z, 1442695.04f, -1442711.04f);
    pen_lds[i0 + 7] = fmaf(m1.w, 1442695.04f, -1442711.04f);
  }

  const int q0 = qt * 128 + wv * 32;

  s16x8 qf[4];
  {
    const __hip_bfloat16* qp =
        Qb + (size_t)(b * 2048 + q0 + l31) * 1024 + h * 64 + hi * 8;
#pragma unroll
    for (int d = 0; d < 4; ++d) qf[d] = *(const s16x8*)(qp + d * 16);
  }

  f32x16 oa0, oa1;
#pragma unroll
  for (int i = 0; i < 16; ++i) { oa0[i] = 0.f; oa1[i] = 0.f; }
  float lsum[4] = {0.f, 0.f, 0.f, 0.f};

  __syncthreads();

  for (int t = 0; t < 32; ++t) {
    const int cur = t & 1;
    if (t < 31) {
      const size_t kadv = (size_t)(t + 1) << 17;
      const size_t vadv = (size_t)(t + 1) << 7;
#pragma unroll
      for (int p = 0; p < 2; ++p) {
        load_lds16(kg[p] + kadv, &K_lds[cur ^ 1][(p * 4 + wv) * 512]);
        load_lds16(vg[p] + vadv, &V_lds[cur ^ 1][(p * 4 + wv) * 512]);
      }
    }

    const char* kb = (const char*)K_lds[cur];
    f32x16 sa[2];
#pragma unroll
    for (int i = 0; i < 16; ++i) { sa[0][i] = 0.f; sa[1][i] = 0.f; }
    {
      s16x8 kf[4];
#pragma unroll
      for (int i = 0; i < 4; ++i) kf[i] = *(const s16x8*)(kb + offs[i]);
      __builtin_amdgcn_s_setprio(1);
#pragma unroll
      for (int d = 0; d < 4; ++d) sa[0] = mfma32(kf[d], qf[d], sa[0]);
      __builtin_amdgcn_s_setprio(0);
#pragma unroll
      for (int i = 0; i < 4; ++i) kf[i] = *(const s16x8*)(kb + offs[4 + i]);
      __builtin_amdgcn_s_setprio(1);
#pragma unroll
      for (int d = 0; d < 4; ++d) sa[1] = mfma32(kf[d], qf[d], sa[1]);
      __builtin_amdgcn_s_setprio(0);
    }

    const int k0 = t << 6;
    float pq[32];
#pragma unroll
    for (int s = 0; s < 2; ++s)
#pragma unroll
      for (int a = 0; a < 4; ++a) {
        const f32x4 pn = *(const f32x4*)&pen_lds[k0 + s * 32 + a * 8 + hi * 4];
#pragma unroll
        for (int r = 0; r < 4; ++r) {
          const float p =
              exp2fast(fmaf(sa[s][a * 4 + r], 0.18033688011112042f, pn[r]));
          pq[s * 16 + a * 4 + r] = p;
          lsum[r] += p;
        }
      }

    s16x8 pb[4];
#pragma unroll
    for (int ks = 0; ks < 4; ++ks) {
      const int base = (ks >> 1) * 16 + (ks & 1) * 8;
      const unsigned wa0 = cvtpk_bf16(pq[base + 0], pq[base + 1]);
      const unsigned wa1 = cvtpk_bf16(pq[base + 2], pq[base + 3]);
      const unsigned wb0 = cvtpk_bf16(pq[base + 4], pq[base + 5]);
      const unsigned wb1 = cvtpk_bf16(pq[base + 6], pq[base + 7]);
      unsigned x0, y0, x1, y1;
      plswap2(wa0, wb0, hi, x0, y0);
      plswap2(wa1, wb1, hi, x1, y1);
      u32x4 u = {x0, x1, y0, y1};
      pb[ks] = __builtin_bit_cast(s16x8, u);
    }

    const char* vb = (const char*)V_lds[cur];
    {
      s16x8 vf[4];
#pragma unroll
      for (int i = 0; i < 4; ++i) vf[i] = *(const s16x8*)(vb + offs[i]);
      __builtin_amdgcn_s_setprio(1);
#pragma unroll
      for (int ks = 0; ks < 4; ++ks) oa0 = mfma32(vf[ks], pb[ks], oa0);
      __builtin_amdgcn_s_setprio(0);
#pragma unroll
      for (int i = 0; i < 4; ++i) vf[i] = *(const s16x8*)(vb + offs[4 + i]);
      __builtin_amdgcn_s_setprio(1);
#pragma unroll
      for (int ks = 0; ks < 4; ++ks) oa1 = mfma32(vf[ks], pb[ks], oa1);
      __builtin_amdgcn_s_setprio(0);
    }

    __syncthreads();
  }

  float lrun = (lsum[0] + lsum[1]) + (lsum[2] + lsum[3]);
  lrun += __shfl_xor(lrun, 32);
  const float inv = 1.0f / lrun;
  __hip_bfloat16* cp = ctx + (size_t)(b * 2048 + q0 + l31) * 1024 + h * 64 + hi * 4;
#pragma unroll
  for (int dt = 0; dt < 2; ++dt) {
#pragma unroll
    for (int g = 0; g < 4; ++g) {
      const float v0 = (dt ? oa1[4 * g + 0] : oa0[4 * g + 0]) * inv;
      const float v1 = (dt ? oa1[4 * g + 1] : oa0[4 * g + 1]) * inv;
      const float v2 = (dt ? oa1[4 * g + 2] : oa0[4 * g + 2]) * inv;
      const float v3 = (dt ? oa1[4 * g + 3] : oa0[4 * g + 3]) * inv;
      u32x2 u;
      u[0] = cvtpk_bf16(v0, v1);
      u[1] = cvtpk_bf16(v2, v3);
      *(u32x2*)(cp + dt * 32 + g * 8) = u;
    }
  }
}

// ---------------- launch ----------------
extern "C" void kernel_launch(void* const* d_in, const int* in_sizes, int n_in,
                              void* d_out, int out_size, void* d_ws, size_t ws_size,
                              hipStream_t stream) {
  const float* X    = (const float*)d_in[0];
  const float* mask = (const float*)d_in[1];
  const float* Wq   = (const float*)d_in[2];
  const float* bq   = (const float*)d_in[3];
  const float* Wk   = (const float*)d_in[4];
  const float* bk   = (const float*)d_in[5];
  const float* Wv   = (const float*)d_in[6];
  const float* bvv  = (const float*)d_in[7];
  const float* Wo   = (const float*)d_in[8];
  const float* bo   = (const float*)d_in[9];
  float* out = (float*)d_out;
  char* ws = (char*)d_ws;

  __hip_bfloat16* Xb   = (__hip_bfloat16*)(ws + 0);        // 16 MiB, reused as ctx
  __hip_bfloat16* ctx  = Xb;
  __hip_bfloat16* Wcat = (__hip_bfloat16*)(ws + 16777216); // Wq^T|Wk^T|Wv^T|Wo^T (8 MiB)
  __hip_bfloat16* Wot  = (__hip_bfloat16*)(ws + 23068672);
  __hip_bfloat16* Qb   = (__hip_bfloat16*)(ws + 25165824);
  __hip_bfloat16* Kb   = (__hip_bfloat16*)(ws + 41943040);
  __hip_bfloat16* Vt   = (__hip_bfloat16*)(ws + 58720256);

  cvt_all<<<9216, 256, 0, stream>>>(X, Wq, Wk, Wv, Wo, Xb, Wcat);

  gemm_qkv<<<1536, 256, 0, stream>>>(Xb, Wcat, bq, bk, bvv, Qb, Kb, Vt);

  attn32<<<1024, 256, 0, stream>>>(Qb, Kb, Vt, mask, ctx);

  gemm_out<<<512, 256, 0, stream>>>(ctx, Wot, bo, out);
}

// Round 13
// 186.560 us; speedup vs baseline: 1.1359x; 1.0039x over previous
//
#include <hip/hip_runtime.h>
#include <hip/hip_bf16.h>
#include <stdint.h>

// ---------------- types ----------------
typedef __bf16 bf16x8 __attribute__((ext_vector_type(8)));
typedef short  s16x8  __attribute__((ext_vector_type(8)));
typedef float  f32x4  __attribute__((ext_vector_type(4)));
typedef float  f32x16 __attribute__((ext_vector_type(16)));
typedef unsigned int u32x2 __attribute__((ext_vector_type(2)));
typedef unsigned int u32x4 __attribute__((ext_vector_type(4)));

__device__ __forceinline__ f32x4 mfma16(s16x8 a, s16x8 b, f32x4 c) {
  return __builtin_amdgcn_mfma_f32_16x16x32_bf16(
      __builtin_bit_cast(bf16x8, a), __builtin_bit_cast(bf16x8, b), c, 0, 0, 0);
}
__device__ __forceinline__ f32x16 mfma32(s16x8 a, s16x8 b, f32x16 c) {
  return __builtin_amdgcn_mfma_f32_32x32x16_bf16(
      __builtin_bit_cast(bf16x8, a), __builtin_bit_cast(bf16x8, b), c, 0, 0, 0);
}

__device__ __forceinline__ void load_lds16(const void* g, void* l) {
  __builtin_amdgcn_global_load_lds(
      (const __attribute__((address_space(1))) void*)g,
      (__attribute__((address_space(3))) void*)l,
      16, 0, 0);
}

__device__ __forceinline__ float exp2fast(float x) {
  float r; asm("v_exp_f32 %0, %1" : "=v"(r) : "v"(x)); return r;
}
__device__ __forceinline__ unsigned cvtpk_bf16(float lo, float hi) {
  unsigned r; asm("v_cvt_pk_bf16_f32 %0, %1, %2" : "=v"(r) : "v"(lo), "v"(hi)); return r;
}
__device__ __forceinline__ void plswap2(unsigned a, unsigned b, int hi,
                                        unsigned& x, unsigned& y) {
#if __has_builtin(__builtin_amdgcn_permlane32_swap)
  auto r = __builtin_amdgcn_permlane32_swap(a, b, false, false);
  x = (unsigned)r[0]; y = (unsigned)r[1];
#else
  unsigned ax = (unsigned)__shfl_xor((int)a, 32);
  unsigned bx = (unsigned)__shfl_xor((int)b, 32);
  x = hi ? bx : a;
  y = hi ? b : ax;
#endif
}

// ---------------- fused conversion kernel ----------------
// blocks [0,8192): X f32 -> Xb bf16 (1024 elems/block)
// blocks [8192,9216): weight sel=(blk>>8)&3, 64x64 LDS tile transpose f32->bf16
__global__ void cvt_all(const float* __restrict__ X,
                        const float* __restrict__ W0, const float* __restrict__ W1,
                        const float* __restrict__ W2, const float* __restrict__ W3,
                        __hip_bfloat16* __restrict__ Xb,
                        __hip_bfloat16* __restrict__ Wcat) {
  __shared__ float t[64][65];
  const int blk = blockIdx.x;
  if (blk < 8192) {
    int i = (blk * 256 + threadIdx.x) << 2;
    float4 v = *(const float4*)(X + i);
    Xb[i + 0] = __float2bfloat16(v.x);
    Xb[i + 1] = __float2bfloat16(v.y);
    Xb[i + 2] = __float2bfloat16(v.z);
    Xb[i + 3] = __float2bfloat16(v.w);
    return;
  }
  const int wblk = blk - 8192;
  const int sel = wblk >> 8;
  const int bid = wblk & 255;
  const float* in = sel == 0 ? W0 : sel == 1 ? W1 : sel == 2 ? W2 : W3;
  __hip_bfloat16* out = Wcat + (size_t)sel * 1048576;
  const int tx = threadIdx.x & 63, ty = threadIdx.x >> 6;  // ty 0..3
  const int bk = bid & 15, bn = bid >> 4;
  const int k0 = bk * 64, n0 = bn * 64;
#pragma unroll
  for (int j = 0; j < 16; ++j)
    t[ty + j * 4][tx] = in[(size_t)(k0 + ty + j * 4) * 1024 + n0 + tx];
  __syncthreads();
#pragma unroll
  for (int j = 0; j < 16; ++j)
    out[(size_t)(n0 + ty + j * 4) * 1024 + k0 + tx] =
        __float2bfloat16(t[tx][ty + j * 4]);
}

// ---------------- fused QKV GEMM (unchanged) ----------------
__launch_bounds__(256, 2)
__global__ void gemm_qkv(const __hip_bfloat16* __restrict__ A,
                         const __hip_bfloat16* __restrict__ Bt,
                         const float* __restrict__ bq,
                         const float* __restrict__ bk,
                         const float* __restrict__ bv,
                         __hip_bfloat16* __restrict__ Qb,
                         __hip_bfloat16* __restrict__ Kb,
                         __hip_bfloat16* __restrict__ Vt) {
  __shared__ __align__(16) __hip_bfloat16 As[128 * 64];
  __shared__ __align__(16) __hip_bfloat16 Bs[128 * 64];
  const int tid  = threadIdx.x;
  const int lane = tid & 63;
  const int wv   = tid >> 6;
  const int l15  = lane & 15;
  const int lhi  = lane >> 4;

  const int bid = blockIdx.x;
  const int lb = (bid & 7) * 192 + (bid >> 3);
  const int bm = lb / 24;
  const int bn = lb % 24;
  const int m0 = bm << 7, n0 = bn << 7;
  const int wr = wv >> 1, wc = wv & 1;

  f32x4 acc[4][4];
  const f32x4 z = {0.f, 0.f, 0.f, 0.f};
#pragma unroll
  for (int i = 0; i < 4; ++i)
#pragma unroll
    for (int j = 0; j < 4; ++j) acc[i][j] = z;

  const int lrow = lane >> 3;
  const int seg2 = (lane & 7) ^ lrow;

  for (int kt = 0; kt < 16; ++kt) {
    __syncthreads();
    const int gk = (kt << 6) + (seg2 << 3);
#pragma unroll
    for (int j = 0; j < 4; ++j) {
      const int c = (wv << 2) + j;
      const int row = (c << 3) + lrow;
      load_lds16(A  + (((size_t)(m0 + row)) << 10) + gk, &As[c << 9]);
      load_lds16(Bt + (((size_t)(n0 + row)) << 10) + gk, &Bs[c << 9]);
    }
    __syncthreads();

#pragma unroll
    for (int kk = 0; kk < 2; ++kk) {
      s16x8 af[4], bfr[4];
#pragma unroll
      for (int mi = 0; mi < 4; ++mi) {
        const int row = (wr << 6) + (mi << 4) + l15;
        const int off = (row << 7) + ((((kk << 2) | lhi) ^ (row & 7)) << 4);
        af[mi] = *(const s16x8*)((const char*)As + off);
      }
#pragma unroll
      for (int ni = 0; ni < 4; ++ni) {
        const int row = (wc << 6) + (ni << 4) + l15;
        const int off = (row << 7) + ((((kk << 2) | lhi) ^ (row & 7)) << 4);
        bfr[ni] = *(const s16x8*)((const char*)Bs + off);
      }
#pragma unroll
      for (int mi = 0; mi < 4; ++mi)
#pragma unroll
        for (int ni = 0; ni < 4; ++ni)
          acc[mi][ni] = mfma16(af[mi], bfr[ni], acc[mi][ni]);
    }
  }

  const int sel = n0 >> 10;  // 0=Q, 1=K, 2=V (block-uniform)
  const float* bp = sel == 0 ? bq : sel == 1 ? bk : bv;
#pragma unroll
  for (int ni = 0; ni < 4; ++ni) {
    const int col = n0 + (wc << 6) + (ni << 4) + l15;
    const int c10 = col & 1023;
    const float bval = bp[c10];
    if (sel == 2) {
      const int h = c10 >> 6, d = c10 & 63;
#pragma unroll
      for (int mi = 0; mi < 4; ++mi) {
        const int row0 = m0 + (wr << 6) + (mi << 4) + (lhi << 2);
#pragma unroll
        for (int r = 0; r < 4; ++r) {
          const int row = row0 + r;
          const int bb = row >> 11, s = row & 2047;
          Vt[(((size_t)(bb * 16 + h) * 64 + d) << 11) + s] =
              __float2bfloat16(acc[mi][ni][r] + bval);
        }
      }
    } else {
      __hip_bfloat16* dst = sel == 0 ? Qb : Kb;
#pragma unroll
      for (int mi = 0; mi < 4; ++mi) {
        const int row0 = m0 + (wr << 6) + (mi << 4) + (lhi << 2);
#pragma unroll
        for (int r = 0; r < 4; ++r)
          dst[(((size_t)(row0 + r)) << 10) + c10] =
              __float2bfloat16(acc[mi][ni][r] + bval);
      }
    }
  }
}

// ---------------- out-projection GEMM (unchanged) ----------------
__launch_bounds__(256, 2)
__global__ void gemm_out(const __hip_bfloat16* __restrict__ A,
                         const __hip_bfloat16* __restrict__ Bt,
                         const float* __restrict__ bias,
                         float* __restrict__ Cout) {
  __shared__ __align__(16) __hip_bfloat16 As[128 * 64];
  __shared__ __align__(16) __hip_bfloat16 Bs[128 * 64];
  const int tid  = threadIdx.x;
  const int lane = tid & 63;
  const int wv   = tid >> 6;
  const int l15  = lane & 15;
  const int lhi  = lane >> 4;

  const int bid = blockIdx.x;
  const int lb = (bid & 7) * 64 + (bid >> 3);
  const int bm = lb >> 3;
  const int bn = lb & 7;
  const int m0 = bm << 7, n0 = bn << 7;
  const int wr = wv >> 1, wc = wv & 1;

  f32x4 acc[4][4];
  const f32x4 z = {0.f, 0.f, 0.f, 0.f};
#pragma unroll
  for (int i = 0; i < 4; ++i)
#pragma unroll
    for (int j = 0; j < 4; ++j) acc[i][j] = z;

  const int lrow = lane >> 3;
  const int seg2 = (lane & 7) ^ lrow;

  for (int kt = 0; kt < 16; ++kt) {
    __syncthreads();
    const int gk = (kt << 6) + (seg2 << 3);
#pragma unroll
    for (int j = 0; j < 4; ++j) {
      const int c = (wv << 2) + j;
      const int row = (c << 3) + lrow;
      load_lds16(A  + (((size_t)(m0 + row)) << 10) + gk, &As[c << 9]);
      load_lds16(Bt + (((size_t)(n0 + row)) << 10) + gk, &Bs[c << 9]);
    }
    __syncthreads();

#pragma unroll
    for (int kk = 0; kk < 2; ++kk) {
      s16x8 af[4], bfr[4];
#pragma unroll
      for (int mi = 0; mi < 4; ++mi) {
        const int row = (wr << 6) + (mi << 4) + l15;
        const int off = (row << 7) + ((((kk << 2) | lhi) ^ (row & 7)) << 4);
        af[mi] = *(const s16x8*)((const char*)As + off);
      }
#pragma unroll
      for (int ni = 0; ni < 4; ++ni) {
        const int row = (wc << 6) + (ni << 4) + l15;
        const int off = (row << 7) + ((((kk << 2) | lhi) ^ (row & 7)) << 4);
        bfr[ni] = *(const s16x8*)((const char*)Bs + off);
      }
#pragma unroll
      for (int mi = 0; mi < 4; ++mi)
#pragma unroll
        for (int ni = 0; ni < 4; ++ni)
          acc[mi][ni] = mfma16(af[mi], bfr[ni], acc[mi][ni]);
    }
  }

#pragma unroll
  for (int ni = 0; ni < 4; ++ni) {
    const int col = n0 + (wc << 6) + (ni << 4) + l15;
    const float bval = bias[col];
#pragma unroll
    for (int mi = 0; mi < 4; ++mi) {
      const int row0 = m0 + (wr << 6) + (mi << 4) + (lhi << 2);
#pragma unroll
      for (int r = 0; r < 4; ++r)
        Cout[(((size_t)(row0 + r)) << 10) + col] = acc[mi][ni][r] + bval;
    }
  }
}

// ---------------- flash attention: 8-wave blocks (256 q-rows), r8 inner loop ----------------
// Qb,Kb: [B*S][1024] bf16; Vt: [B,H,HD,S] bf16; mask: [B,S] f32; ctx: [B*S][1024] bf16
// Block = 8 waves, one (b,h), 256 q-rows. Wave owns 32 q (q = lane&31).
// K/V 64x64 bf16 tiles double-buffered in LDS (XOR-swizzled via pre-swizzled
// global source), staged 1 load/wave, shared by all 8 waves.
// p = exp2(s*log2e/8 + pen - 16); row-constant factor cancels in normalization.
__launch_bounds__(512, 4)
__global__ void attn32(const __hip_bfloat16* __restrict__ Qb,
                       const __hip_bfloat16* __restrict__ Kb,
                       const __hip_bfloat16* __restrict__ Vt,
                       const float* __restrict__ mask,
                       __hip_bfloat16* __restrict__ ctx) {
  __shared__ __align__(16) __hip_bfloat16 K_lds[2][4096];  // [64 k][64 d] swizzled
  __shared__ __align__(16) __hip_bfloat16 V_lds[2][4096];  // [64 d][64 k] swizzled
  __shared__ float pen_lds[2048];

  const int tid = threadIdx.x;
  const int lane = tid & 63, wv = tid >> 6;       // wv 0..7
  const int l31 = lane & 31, hi = lane >> 5;

  // grid 512 = B*H*(2048/256); XCD-bijective: XCD x owns 64 consecutive lb = 8 (b,h) groups
  const int bid = blockIdx.x;
  const int lb = (bid & 7) * 64 + (bid >> 3);
  const int qt = lb & 7;                          // 8 q-tiles of 256 rows
  const int bh = lb >> 3;
  const int h = bh & 15, b = bh >> 4;

  const int srow = lane >> 3;
  const int sseg = (lane & 7) ^ srow;
  // each wave stages one 1KB chunk (rows wv*8..wv*8+7) of K and of V
  const int crow = wv * 8 + srow;
  const char* kg = (const char*)Kb +
                   (((size_t)(b * 2048 + crow) << 10) + h * 64 + sseg * 8) * 2;
  const char* vg = (const char*)Vt +
                   (((size_t)(bh * 64 + crow) << 11) + sseg * 8) * 2;

  int offs[8];
#pragma unroll
  for (int i = 0; i < 8; ++i) {
    const int row7 = l31 & 7;
    offs[i] = ((i >> 2) << 12) + (l31 << 7) +
              ((((((i & 3) << 1) | hi)) ^ row7) << 4);
  }

  load_lds16(kg, &K_lds[0][wv * 512]);
  load_lds16(vg, &V_lds[0][wv * 512]);
  {
    const float* mrow = mask + b * 2048;
    const int i0 = tid * 4;
    float4 m = *(const float4*)(mrow + i0);
    pen_lds[i0 + 0] = fmaf(m.x, 1442695.04f, -1442711.04f);
    pen_lds[i0 + 1] = fmaf(m.y, 1442695.04f, -1442711.04f);
    pen_lds[i0 + 2] = fmaf(m.z, 1442695.04f, -1442711.04f);
    pen_lds[i0 + 3] = fmaf(m.w, 1442695.04f, -1442711.04f);
  }

  const int q0 = qt * 256 + wv * 32;

  s16x8 qf[4];
  {
    const __hip_bfloat16* qp =
        Qb + (size_t)(b * 2048 + q0 + l31) * 1024 + h * 64 + hi * 8;
#pragma unroll
    for (int d = 0; d < 4; ++d) qf[d] = *(const s16x8*)(qp + d * 16);
  }

  f32x16 oa0, oa1;
#pragma unroll
  for (int i = 0; i < 16; ++i) { oa0[i] = 0.f; oa1[i] = 0.f; }
  float lsum[4] = {0.f, 0.f, 0.f, 0.f};

  __syncthreads();

  for (int t = 0; t < 32; ++t) {
    const int cur = t & 1;
    if (t < 31) {
      const size_t kadv = (size_t)(t + 1) << 17;   // 64 K-rows * 2048 B
      const size_t vadv = (size_t)(t + 1) << 7;    // 64 k-cols * 2 B
      load_lds16(kg + kadv, &K_lds[cur ^ 1][wv * 512]);
      load_lds16(vg + vadv, &V_lds[cur ^ 1][wv * 512]);
    }

    const char* kb = (const char*)K_lds[cur];
    f32x16 sa[2];
#pragma unroll
    for (int i = 0; i < 16; ++i) { sa[0][i] = 0.f; sa[1][i] = 0.f; }
    {
      s16x8 kf[4];
#pragma unroll
      for (int i = 0; i < 4; ++i) kf[i] = *(const s16x8*)(kb + offs[i]);
      __builtin_amdgcn_s_setprio(1);
#pragma unroll
      for (int d = 0; d < 4; ++d) sa[0] = mfma32(kf[d], qf[d], sa[0]);
      __builtin_amdgcn_s_setprio(0);
#pragma unroll
      for (int i = 0; i < 4; ++i) kf[i] = *(const s16x8*)(kb + offs[4 + i]);
      __builtin_amdgcn_s_setprio(1);
#pragma unroll
      for (int d = 0; d < 4; ++d) sa[1] = mfma32(kf[d], qf[d], sa[1]);
      __builtin_amdgcn_s_setprio(0);
    }

    const int k0 = t << 6;
    float pq[32];
#pragma unroll
    for (int s = 0; s < 2; ++s)
#pragma unroll
      for (int a = 0; a < 4; ++a) {
        const f32x4 pn = *(const f32x4*)&pen_lds[k0 + s * 32 + a * 8 + hi * 4];
#pragma unroll
        for (int r = 0; r < 4; ++r) {
          const float p =
              exp2fast(fmaf(sa[s][a * 4 + r], 0.18033688011112042f, pn[r]));
          pq[s * 16 + a * 4 + r] = p;
          lsum[r] += p;
        }
      }

    s16x8 pb[4];
#pragma unroll
    for (int ks = 0; ks < 4; ++ks) {
      const int base = (ks >> 1) * 16 + (ks & 1) * 8;
      const unsigned wa0 = cvtpk_bf16(pq[base + 0], pq[base + 1]);
      const unsigned wa1 = cvtpk_bf16(pq[base + 2], pq[base + 3]);
      const unsigned wb0 = cvtpk_bf16(pq[base + 4], pq[base + 5]);
      const unsigned wb1 = cvtpk_bf16(pq[base + 6], pq[base + 7]);
      unsigned x0, y0, x1, y1;
      plswap2(wa0, wb0, hi, x0, y0);
      plswap2(wa1, wb1, hi, x1, y1);
      u32x4 u = {x0, x1, y0, y1};
      pb[ks] = __builtin_bit_cast(s16x8, u);
    }

    const char* vb = (const char*)V_lds[cur];
    {
      s16x8 vf[4];
#pragma unroll
      for (int i = 0; i < 4; ++i) vf[i] = *(const s16x8*)(vb + offs[i]);
      __builtin_amdgcn_s_setprio(1);
#pragma unroll
      for (int ks = 0; ks < 4; ++ks) oa0 = mfma32(vf[ks], pb[ks], oa0);
      __builtin_amdgcn_s_setprio(0);
#pragma unroll
      for (int i = 0; i < 4; ++i) vf[i] = *(const s16x8*)(vb + offs[4 + i]);
      __builtin_amdgcn_s_setprio(1);
#pragma unroll
      for (int ks = 0; ks < 4; ++ks) oa1 = mfma32(vf[ks], pb[ks], oa1);
      __builtin_amdgcn_s_setprio(0);
    }

    __syncthreads();
  }

  float lrun = (lsum[0] + lsum[1]) + (lsum[2] + lsum[3]);
  lrun += __shfl_xor(lrun, 32);
  const float inv = 1.0f / lrun;
  __hip_bfloat16* cp = ctx + (size_t)(b * 2048 + q0 + l31) * 1024 + h * 64 + hi * 4;
#pragma unroll
  for (int dt = 0; dt < 2; ++dt) {
#pragma unroll
    for (int g = 0; g < 4; ++g) {
      const float v0 = (dt ? oa1[4 * g + 0] : oa0[4 * g + 0]) * inv;
      const float v1 = (dt ? oa1[4 * g + 1] : oa0[4 * g + 1]) * inv;
      const float v2 = (dt ? oa1[4 * g + 2] : oa0[4 * g + 2]) * inv;
      const float v3 = (dt ? oa1[4 * g + 3] : oa0[4 * g + 3]) * inv;
      u32x2 u;
      u[0] = cvtpk_bf16(v0, v1);
      u[1] = cvtpk_bf16(v2, v3);
      *(u32x2*)(cp + dt * 32 + g * 8) = u;
    }
  }
}

// ---------------- launch ----------------
extern "C" void kernel_launch(void* const* d_in, const int* in_sizes, int n_in,
                              void* d_out, int out_size, void* d_ws, size_t ws_size,
                              hipStream_t stream) {
  const float* X    = (const float*)d_in[0];
  const float* mask = (const float*)d_in[1];
  const float* Wq   = (const float*)d_in[2];
  const float* bq   = (const float*)d_in[3];
  const float* Wk   = (const float*)d_in[4];
  const float* bk   = (const float*)d_in[5];
  const float* Wv   = (const float*)d_in[6];
  const float* bvv  = (const float*)d_in[7];
  const float* Wo   = (const float*)d_in[8];
  const float* bo   = (const float*)d_in[9];
  float* out = (float*)d_out;
  char* ws = (char*)d_ws;

  __hip_bfloat16* Xb   = (__hip_bfloat16*)(ws + 0);        // 16 MiB, reused as ctx
  __hip_bfloat16* ctx  = Xb;
  __hip_bfloat16* Wcat = (__hip_bfloat16*)(ws + 16777216); // Wq^T|Wk^T|Wv^T|Wo^T (8 MiB)
  __hip_bfloat16* Wot  = (__hip_bfloat16*)(ws + 23068672);
  __hip_bfloat16* Qb   = (__hip_bfloat16*)(ws + 25165824);
  __hip_bfloat16* Kb   = (__hip_bfloat16*)(ws + 41943040);
  __hip_bfloat16* Vt   = (__hip_bfloat16*)(ws + 58720256);

  cvt_all<<<9216, 256, 0, stream>>>(X, Wq, Wk, Wv, Wo, Xb, Wcat);

  gemm_qkv<<<1536, 256, 0, stream>>>(Xb, Wcat, bq, bk, bvv, Qb, Kb, Vt);

  attn32<<<512, 512, 0, stream>>>(Qb, Kb, Vt, mask, ctx);

  gemm_out<<<512, 256, 0, stream>>>(ctx, Wot, bo, out);
}

// Round 14
// 178.165 us; speedup vs baseline: 1.1894x; 1.0471x over previous
//
#include <hip/hip_runtime.h>
#include <hip/hip_bf16.h>
#include <stdint.h>

// ---------------- types ----------------
typedef __bf16 bf16x8 __attribute__((ext_vector_type(8)));
typedef short  s16x8  __attribute__((ext_vector_type(8)));
typedef float  f32x4  __attribute__((ext_vector_type(4)));
typedef float  f32x16 __attribute__((ext_vector_type(16)));
typedef unsigned int u32x2 __attribute__((ext_vector_type(2)));
typedef unsigned int u32x4 __attribute__((ext_vector_type(4)));

__device__ __forceinline__ f32x4 mfma16(s16x8 a, s16x8 b, f32x4 c) {
  return __builtin_amdgcn_mfma_f32_16x16x32_bf16(
      __builtin_bit_cast(bf16x8, a), __builtin_bit_cast(bf16x8, b), c, 0, 0, 0);
}
__device__ __forceinline__ f32x16 mfma32(s16x8 a, s16x8 b, f32x16 c) {
  return __builtin_amdgcn_mfma_f32_32x32x16_bf16(
      __builtin_bit_cast(bf16x8, a), __builtin_bit_cast(bf16x8, b), c, 0, 0, 0);
}

__device__ __forceinline__ void load_lds16(const void* g, void* l) {
  __builtin_amdgcn_global_load_lds(
      (const __attribute__((address_space(1))) void*)g,
      (__attribute__((address_space(3))) void*)l,
      16, 0, 0);
}

__device__ __forceinline__ float exp2fast(float x) {
  float r; asm("v_exp_f32 %0, %1" : "=v"(r) : "v"(x)); return r;
}
__device__ __forceinline__ unsigned cvtpk_bf16(float lo, float hi) {
  unsigned r; asm("v_cvt_pk_bf16_f32 %0, %1, %2" : "=v"(r) : "v"(lo), "v"(hi)); return r;
}
__device__ __forceinline__ void plswap2(unsigned a, unsigned b, int hi,
                                        unsigned& x, unsigned& y) {
#if __has_builtin(__builtin_amdgcn_permlane32_swap)
  auto r = __builtin_amdgcn_permlane32_swap(a, b, false, false);
  x = (unsigned)r[0]; y = (unsigned)r[1];
#else
  unsigned ax = (unsigned)__shfl_xor((int)a, 32);
  unsigned bx = (unsigned)__shfl_xor((int)b, 32);
  x = hi ? bx : a;
  y = hi ? b : ax;
#endif
}

// ---------------- fused conversion kernel ----------------
// blocks [0,8192): X f32 -> Xb bf16 (1024 elems/block)
// blocks [8192,9216): weight sel=(blk>>8)&3, 64x64 LDS tile transpose f32->bf16
__global__ void cvt_all(const float* __restrict__ X,
                        const float* __restrict__ W0, const float* __restrict__ W1,
                        const float* __restrict__ W2, const float* __restrict__ W3,
                        __hip_bfloat16* __restrict__ Xb,
                        __hip_bfloat16* __restrict__ Wcat) {
  __shared__ float t[64][65];
  const int blk = blockIdx.x;
  if (blk < 8192) {
    int i = (blk * 256 + threadIdx.x) << 2;
    float4 v = *(const float4*)(X + i);
    Xb[i + 0] = __float2bfloat16(v.x);
    Xb[i + 1] = __float2bfloat16(v.y);
    Xb[i + 2] = __float2bfloat16(v.z);
    Xb[i + 3] = __float2bfloat16(v.w);
    return;
  }
  const int wblk = blk - 8192;
  const int sel = wblk >> 8;
  const int bid = wblk & 255;
  const float* in = sel == 0 ? W0 : sel == 1 ? W1 : sel == 2 ? W2 : W3;
  __hip_bfloat16* out = Wcat + (size_t)sel * 1048576;
  const int tx = threadIdx.x & 63, ty = threadIdx.x >> 6;  // ty 0..3
  const int bk = bid & 15, bn = bid >> 4;
  const int k0 = bk * 64, n0 = bn * 64;
#pragma unroll
  for (int j = 0; j < 16; ++j)
    t[ty + j * 4][tx] = in[(size_t)(k0 + ty + j * 4) * 1024 + n0 + tx];
  __syncthreads();
#pragma unroll
  for (int j = 0; j < 16; ++j)
    out[(size_t)(n0 + ty + j * 4) * 1024 + k0 + tx] =
        __float2bfloat16(t[tx][ty + j * 4]);
}

// ---------------- fused QKV GEMM (Q pre-scaled by log2(e)/8) ----------------
__launch_bounds__(256, 2)
__global__ void gemm_qkv(const __hip_bfloat16* __restrict__ A,
                         const __hip_bfloat16* __restrict__ Bt,
                         const float* __restrict__ bq,
                         const float* __restrict__ bk,
                         const float* __restrict__ bv,
                         __hip_bfloat16* __restrict__ Qb,
                         __hip_bfloat16* __restrict__ Kb,
                         __hip_bfloat16* __restrict__ Vt) {
  __shared__ __align__(16) __hip_bfloat16 As[128 * 64];
  __shared__ __align__(16) __hip_bfloat16 Bs[128 * 64];
  const int tid  = threadIdx.x;
  const int lane = tid & 63;
  const int wv   = tid >> 6;
  const int l15  = lane & 15;
  const int lhi  = lane >> 4;

  const int bid = blockIdx.x;
  const int lb = (bid & 7) * 192 + (bid >> 3);
  const int bm = lb / 24;
  const int bn = lb % 24;
  const int m0 = bm << 7, n0 = bn << 7;
  const int wr = wv >> 1, wc = wv & 1;

  f32x4 acc[4][4];
  const f32x4 z = {0.f, 0.f, 0.f, 0.f};
#pragma unroll
  for (int i = 0; i < 4; ++i)
#pragma unroll
    for (int j = 0; j < 4; ++j) acc[i][j] = z;

  const int lrow = lane >> 3;
  const int seg2 = (lane & 7) ^ lrow;

  for (int kt = 0; kt < 16; ++kt) {
    __syncthreads();
    const int gk = (kt << 6) + (seg2 << 3);
#pragma unroll
    for (int j = 0; j < 4; ++j) {
      const int c = (wv << 2) + j;
      const int row = (c << 3) + lrow;
      load_lds16(A  + (((size_t)(m0 + row)) << 10) + gk, &As[c << 9]);
      load_lds16(Bt + (((size_t)(n0 + row)) << 10) + gk, &Bs[c << 9]);
    }
    __syncthreads();

#pragma unroll
    for (int kk = 0; kk < 2; ++kk) {
      s16x8 af[4], bfr[4];
#pragma unroll
      for (int mi = 0; mi < 4; ++mi) {
        const int row = (wr << 6) + (mi << 4) + l15;
        const int off = (row << 7) + ((((kk << 2) | lhi) ^ (row & 7)) << 4);
        af[mi] = *(const s16x8*)((const char*)As + off);
      }
#pragma unroll
      for (int ni = 0; ni < 4; ++ni) {
        const int row = (wc << 6) + (ni << 4) + l15;
        const int off = (row << 7) + ((((kk << 2) | lhi) ^ (row & 7)) << 4);
        bfr[ni] = *(const s16x8*)((const char*)Bs + off);
      }
#pragma unroll
      for (int mi = 0; mi < 4; ++mi)
#pragma unroll
        for (int ni = 0; ni < 4; ++ni)
          acc[mi][ni] = mfma16(af[mi], bfr[ni], acc[mi][ni]);
    }
  }

  const int sel = n0 >> 10;  // 0=Q, 1=K, 2=V (block-uniform)
  const float* bp = sel == 0 ? bq : sel == 1 ? bk : bv;
  const float qs = sel == 0 ? 0.18033688011112042f : 1.0f;  // log2(e)/8 on Q only
#pragma unroll
  for (int ni = 0; ni < 4; ++ni) {
    const int col = n0 + (wc << 6) + (ni << 4) + l15;
    const int c10 = col & 1023;
    const float bval = bp[c10];
    if (sel == 2) {
      const int h = c10 >> 6, d = c10 & 63;
#pragma unroll
      for (int mi = 0; mi < 4; ++mi) {
        const int row0 = m0 + (wr << 6) + (mi << 4) + (lhi << 2);
#pragma unroll
        for (int r = 0; r < 4; ++r) {
          const int row = row0 + r;
          const int bb = row >> 11, s = row & 2047;
          Vt[(((size_t)(bb * 16 + h) * 64 + d) << 11) + s] =
              __float2bfloat16(acc[mi][ni][r] + bval);
        }
      }
    } else {
      __hip_bfloat16* dst = sel == 0 ? Qb : Kb;
#pragma unroll
      for (int mi = 0; mi < 4; ++mi) {
        const int row0 = m0 + (wr << 6) + (mi << 4) + (lhi << 2);
#pragma unroll
        for (int r = 0; r < 4; ++r)
          dst[(((size_t)(row0 + r)) << 10) + c10] =
              __float2bfloat16((acc[mi][ni][r] + bval) * qs);
      }
    }
  }
}

// ---------------- out-projection GEMM (unchanged) ----------------
__launch_bounds__(256, 2)
__global__ void gemm_out(const __hip_bfloat16* __restrict__ A,
                         const __hip_bfloat16* __restrict__ Bt,
                         const float* __restrict__ bias,
                         float* __restrict__ Cout) {
  __shared__ __align__(16) __hip_bfloat16 As[128 * 64];
  __shared__ __align__(16) __hip_bfloat16 Bs[128 * 64];
  const int tid  = threadIdx.x;
  const int lane = tid & 63;
  const int wv   = tid >> 6;
  const int l15  = lane & 15;
  const int lhi  = lane >> 4;

  const int bid = blockIdx.x;
  const int lb = (bid & 7) * 64 + (bid >> 3);
  const int bm = lb >> 3;
  const int bn = lb & 7;
  const int m0 = bm << 7, n0 = bn << 7;
  const int wr = wv >> 1, wc = wv & 1;

  f32x4 acc[4][4];
  const f32x4 z = {0.f, 0.f, 0.f, 0.f};
#pragma unroll
  for (int i = 0; i < 4; ++i)
#pragma unroll
    for (int j = 0; j < 4; ++j) acc[i][j] = z;

  const int lrow = lane >> 3;
  const int seg2 = (lane & 7) ^ lrow;

  for (int kt = 0; kt < 16; ++kt) {
    __syncthreads();
    const int gk = (kt << 6) + (seg2 << 3);
#pragma unroll
    for (int j = 0; j < 4; ++j) {
      const int c = (wv << 2) + j;
      const int row = (c << 3) + lrow;
      load_lds16(A  + (((size_t)(m0 + row)) << 10) + gk, &As[c << 9]);
      load_lds16(Bt + (((size_t)(n0 + row)) << 10) + gk, &Bs[c << 9]);
    }
    __syncthreads();

#pragma unroll
    for (int kk = 0; kk < 2; ++kk) {
      s16x8 af[4], bfr[4];
#pragma unroll
      for (int mi = 0; mi < 4; ++mi) {
        const int row = (wr << 6) + (mi << 4) + l15;
        const int off = (row << 7) + ((((kk << 2) | lhi) ^ (row & 7)) << 4);
        af[mi] = *(const s16x8*)((const char*)As + off);
      }
#pragma unroll
      for (int ni = 0; ni < 4; ++ni) {
        const int row = (wc << 6) + (ni << 4) + l15;
        const int off = (row << 7) + ((((kk << 2) | lhi) ^ (row & 7)) << 4);
        bfr[ni] = *(const s16x8*)((const char*)Bs + off);
      }
#pragma unroll
      for (int mi = 0; mi < 4; ++mi)
#pragma unroll
        for (int ni = 0; ni < 4; ++ni)
          acc[mi][ni] = mfma16(af[mi], bfr[ni], acc[mi][ni]);
    }
  }

#pragma unroll
  for (int ni = 0; ni < 4; ++ni) {
    const int col = n0 + (wc << 6) + (ni << 4) + l15;
    const float bval = bias[col];
#pragma unroll
    for (int mi = 0; mi < 4; ++mi) {
      const int row0 = m0 + (wr << 6) + (mi << 4) + (lhi << 2);
#pragma unroll
      for (int r = 0; r < 4; ++r)
        Cout[(((size_t)(row0 + r)) << 10) + col] = acc[mi][ni][r] + bval;
    }
  }
}

// ---------------- flash attention: 8-wave blocks, pen-as-C-init softmax ----------------
// Qb: [B*S][1024] bf16 PRE-SCALED by log2(e)/8; Kb: [B*S][1024] bf16;
// Vt: [B,H,HD,S] bf16; mask: [B,S] f32; ctx: [B*S][1024] bf16.
// Block = 8 waves, one (b,h), 256 q-rows. Wave owns 32 q (q = lane&31).
// K/V 64x64 bf16 tiles double-buffered in LDS (XOR-swizzled via pre-swizzled
// global source), staged 1 load/wave. QK accumulator is INITIALIZED with
// pen2 = -1e6*log2e*(1-mask) - 16, so p = exp2(sa) directly (static-C softmax;
// row-constant factor cancels in normalization; no overflow possible).
__launch_bounds__(512, 4)
__global__ void attn32(const __hip_bfloat16* __restrict__ Qb,
                       const __hip_bfloat16* __restrict__ Kb,
                       const __hip_bfloat16* __restrict__ Vt,
                       const float* __restrict__ mask,
                       __hip_bfloat16* __restrict__ ctx) {
  __shared__ __align__(16) __hip_bfloat16 K_lds[2][4096];  // [64 k][64 d] swizzled
  __shared__ __align__(16) __hip_bfloat16 V_lds[2][4096];  // [64 d][64 k] swizzled
  __shared__ float pen_lds[2048];

  const int tid = threadIdx.x;
  const int lane = tid & 63, wv = tid >> 6;       // wv 0..7
  const int l31 = lane & 31, hi = lane >> 5;

  const int bid = blockIdx.x;
  const int lb = (bid & 7) * 64 + (bid >> 3);
  const int qt = lb & 7;
  const int bh = lb >> 3;
  const int h = bh & 15, b = bh >> 4;

  const int srow = lane >> 3;
  const int sseg = (lane & 7) ^ srow;
  const int crow = wv * 8 + srow;
  const char* kg = (const char*)Kb +
                   (((size_t)(b * 2048 + crow) << 10) + h * 64 + sseg * 8) * 2;
  const char* vg = (const char*)Vt +
                   (((size_t)(bh * 64 + crow) << 11) + sseg * 8) * 2;

  int offs[8];
#pragma unroll
  for (int i = 0; i < 8; ++i) {
    const int row7 = l31 & 7;
    offs[i] = ((i >> 2) << 12) + (l31 << 7) +
              ((((((i & 3) << 1) | hi)) ^ row7) << 4);
  }

  load_lds16(kg, &K_lds[0][wv * 512]);
  load_lds16(vg, &V_lds[0][wv * 512]);
  {
    const float* mrow = mask + b * 2048;
    const int i0 = tid * 4;
    float4 m = *(const float4*)(mrow + i0);
    pen_lds[i0 + 0] = fmaf(m.x, 1442695.04f, -1442711.04f);
    pen_lds[i0 + 1] = fmaf(m.y, 1442695.04f, -1442711.04f);
    pen_lds[i0 + 2] = fmaf(m.z, 1442695.04f, -1442711.04f);
    pen_lds[i0 + 3] = fmaf(m.w, 1442695.04f, -1442711.04f);
  }

  const int q0 = qt * 256 + wv * 32;

  s16x8 qf[4];
  {
    const __hip_bfloat16* qp =
        Qb + (size_t)(b * 2048 + q0 + l31) * 1024 + h * 64 + hi * 8;
#pragma unroll
    for (int d = 0; d < 4; ++d) qf[d] = *(const s16x8*)(qp + d * 16);
  }

  f32x16 oa0, oa1;
#pragma unroll
  for (int i = 0; i < 16; ++i) { oa0[i] = 0.f; oa1[i] = 0.f; }
  float lsum[4] = {0.f, 0.f, 0.f, 0.f};

  __syncthreads();

  for (int t = 0; t < 32; ++t) {
    const int cur = t & 1;
    if (t < 31) {
      const size_t kadv = (size_t)(t + 1) << 17;
      const size_t vadv = (size_t)(t + 1) << 7;
      load_lds16(kg + kadv, &K_lds[cur ^ 1][wv * 512]);
      load_lds16(vg + vadv, &V_lds[cur ^ 1][wv * 512]);
    }

    // ---- QK accumulator initialized with penalty (C-operand trick) ----
    // sa reg r of subtile s -> k = 32*s + 8*(r>>2) + 4*hi + (r&3)
    const int k0 = t << 6;
    f32x16 sa[2];
#pragma unroll
    for (int s = 0; s < 2; ++s)
#pragma unroll
      for (int a = 0; a < 4; ++a) {
        const f32x4 pn = *(const f32x4*)&pen_lds[k0 + s * 32 + a * 8 + hi * 4];
#pragma unroll
        for (int r = 0; r < 4; ++r) sa[s][a * 4 + r] = pn[r];
      }

    const char* kb = (const char*)K_lds[cur];
    {
      s16x8 kf[4];
#pragma unroll
      for (int i = 0; i < 4; ++i) kf[i] = *(const s16x8*)(kb + offs[i]);
      __builtin_amdgcn_s_setprio(1);
#pragma unroll
      for (int d = 0; d < 4; ++d) sa[0] = mfma32(kf[d], qf[d], sa[0]);
      __builtin_amdgcn_s_setprio(0);
#pragma unroll
      for (int i = 0; i < 4; ++i) kf[i] = *(const s16x8*)(kb + offs[4 + i]);
      __builtin_amdgcn_s_setprio(1);
#pragma unroll
      for (int d = 0; d < 4; ++d) sa[1] = mfma32(kf[d], qf[d], sa[1]);
      __builtin_amdgcn_s_setprio(0);
    }

    // ---- static-C softmax: p = exp2(sa) (Q pre-scaled; pen already in sa) ----
    float pq[32];
#pragma unroll
    for (int s = 0; s < 2; ++s)
#pragma unroll
      for (int a = 0; a < 4; ++a) {
#pragma unroll
        for (int r = 0; r < 4; ++r) {
          const float p = exp2fast(sa[s][a * 4 + r]);
          pq[s * 16 + a * 4 + r] = p;
          lsum[r] += p;
        }
      }

    s16x8 pb[4];
#pragma unroll
    for (int ks = 0; ks < 4; ++ks) {
      const int base = (ks >> 1) * 16 + (ks & 1) * 8;
      const unsigned wa0 = cvtpk_bf16(pq[base + 0], pq[base + 1]);
      const unsigned wa1 = cvtpk_bf16(pq[base + 2], pq[base + 3]);
      const unsigned wb0 = cvtpk_bf16(pq[base + 4], pq[base + 5]);
      const unsigned wb1 = cvtpk_bf16(pq[base + 6], pq[base + 7]);
      unsigned x0, y0, x1, y1;
      plswap2(wa0, wb0, hi, x0, y0);
      plswap2(wa1, wb1, hi, x1, y1);
      u32x4 u = {x0, x1, y0, y1};
      pb[ks] = __builtin_bit_cast(s16x8, u);
    }

    const char* vb = (const char*)V_lds[cur];
    {
      s16x8 vf[4];
#pragma unroll
      for (int i = 0; i < 4; ++i) vf[i] = *(const s16x8*)(vb + offs[i]);
      __builtin_amdgcn_s_setprio(1);
#pragma unroll
      for (int ks = 0; ks < 4; ++ks) oa0 = mfma32(vf[ks], pb[ks], oa0);
      __builtin_amdgcn_s_setprio(0);
#pragma unroll
      for (int i = 0; i < 4; ++i) vf[i] = *(const s16x8*)(vb + offs[4 + i]);
      __builtin_amdgcn_s_setprio(1);
#pragma unroll
      for (int ks = 0; ks < 4; ++ks) oa1 = mfma32(vf[ks], pb[ks], oa1);
      __builtin_amdgcn_s_setprio(0);
    }

    __syncthreads();
  }

  float lrun = (lsum[0] + lsum[1]) + (lsum[2] + lsum[3]);
  lrun += __shfl_xor(lrun, 32);
  const float inv = 1.0f / lrun;
  __hip_bfloat16* cp = ctx + (size_t)(b * 2048 + q0 + l31) * 1024 + h * 64 + hi * 4;
#pragma unroll
  for (int dt = 0; dt < 2; ++dt) {
#pragma unroll
    for (int g = 0; g < 4; ++g) {
      const float v0 = (dt ? oa1[4 * g + 0] : oa0[4 * g + 0]) * inv;
      const float v1 = (dt ? oa1[4 * g + 1] : oa0[4 * g + 1]) * inv;
      const float v2 = (dt ? oa1[4 * g + 2] : oa0[4 * g + 2]) * inv;
      const float v3 = (dt ? oa1[4 * g + 3] : oa0[4 * g + 3]) * inv;
      u32x2 u;
      u[0] = cvtpk_bf16(v0, v1);
      u[1] = cvtpk_bf16(v2, v3);
      *(u32x2*)(cp + dt * 32 + g * 8) = u;
    }
  }
}

// ---------------- launch ----------------
extern "C" void kernel_launch(void* const* d_in, const int* in_sizes, int n_in,
                              void* d_out, int out_size, void* d_ws, size_t ws_size,
                              hipStream_t stream) {
  const float* X    = (const float*)d_in[0];
  const float* mask = (const float*)d_in[1];
  const float* Wq   = (const float*)d_in[2];
  const float* bq   = (const float*)d_in[3];
  const float* Wk   = (const float*)d_in[4];
  const float* bk   = (const float*)d_in[5];
  const float* Wv   = (const float*)d_in[6];
  const float* bvv  = (const float*)d_in[7];
  const float* Wo   = (const float*)d_in[8];
  const float* bo   = (const float*)d_in[9];
  float* out = (float*)d_out;
  char* ws = (char*)d_ws;

  __hip_bfloat16* Xb   = (__hip_bfloat16*)(ws + 0);        // 16 MiB, reused as ctx
  __hip_bfloat16* ctx  = Xb;
  __hip_bfloat16* Wcat = (__hip_bfloat16*)(ws + 16777216); // Wq^T|Wk^T|Wv^T|Wo^T (8 MiB)
  __hip_bfloat16* Wot  = (__hip_bfloat16*)(ws + 23068672);
  __hip_bfloat16* Qb   = (__hip_bfloat16*)(ws + 25165824);
  __hip_bfloat16* Kb   = (__hip_bfloat16*)(ws + 41943040);
  __hip_bfloat16* Vt   = (__hip_bfloat16*)(ws + 58720256);

  cvt_all<<<9216, 256, 0, stream>>>(X, Wq, Wk, Wv, Wo, Xb, Wcat);

  gemm_qkv<<<1536, 256, 0, stream>>>(Xb, Wcat, bq, bk, bvv, Qb, Kb, Vt);

  attn32<<<512, 512, 0, stream>>>(Qb, Kb, Vt, mask, ctx);

  gemm_out<<<512, 256, 0, stream>>>(ctx, Wot, bo, out);
}